// Round 1
// baseline (734.648 us; speedup 1.0000x reference)
//
#include <hip/hip_runtime.h>
#include <math.h>

// ---------------------------------------------------------------------------
// SimpleTernaryNet forward:
//   tern(w) -> conv3x3(3->16)+b+relu -> maxpool2
//           -> conv3x3(16->32)+b+relu -> maxpool2
//           -> fc(2048->128)+b+relu -> fc(128->10)+b
// All fp32. B = 4096.
// ---------------------------------------------------------------------------

// ---------------- ternarize: blockIdx picks tensor ----------------
// out layouts:
//   tw1 : [16][28]  (row-padded, j<27 valid)
//   tw2 : [ci=16][k=9][co=32]  (transposed for vector co-reads)
//   twf1: [k=2048][n=128]      (transposed for coalesced GEMM B)
//   twf2: [10][128]            (as-is)
__global__ void ternarize_all(const float* __restrict__ w1,
                              const float* __restrict__ w2,
                              const float* __restrict__ wf1,
                              const float* __restrict__ wf2,
                              float* __restrict__ tw1,
                              float* __restrict__ tw2,
                              float* __restrict__ twf1,
                              float* __restrict__ twf2) {
    __shared__ float red[256];
    __shared__ float s_delta, s_alpha;
    const int t = threadIdx.x;
    const float* w;
    int n;
    switch (blockIdx.x) {
        case 0: w = w1;  n = 432;    break;
        case 1: w = w2;  n = 4608;   break;
        case 2: w = wf1; n = 262144; break;
        default: w = wf2; n = 1280;  break;
    }
    // pass 1: mean |w|
    float s = 0.f;
    for (int i = t; i < n; i += 256) s += fabsf(w[i]);
    red[t] = s; __syncthreads();
    for (int o = 128; o > 0; o >>= 1) { if (t < o) red[t] += red[t + o]; __syncthreads(); }
    if (t == 0) s_delta = 0.7f * red[0] / (float)n;
    __syncthreads();
    const float delta = s_delta;
    // pass 2: alpha = sum(|w|*mask)/max(count,1)
    float sa = 0.f, cnt = 0.f;
    for (int i = t; i < n; i += 256) {
        float a = fabsf(w[i]);
        if (a > delta) { sa += a; cnt += 1.f; }
    }
    red[t] = sa; __syncthreads();
    for (int o = 128; o > 0; o >>= 1) { if (t < o) red[t] += red[t + o]; __syncthreads(); }
    const float tot_sa = red[0];
    __syncthreads();
    red[t] = cnt; __syncthreads();
    for (int o = 128; o > 0; o >>= 1) { if (t < o) red[t] += red[t + o]; __syncthreads(); }
    if (t == 0) s_alpha = tot_sa / fmaxf(red[0], 1.0f);
    __syncthreads();
    const float alpha = s_alpha;

    // pass 3: write with per-tensor layout
    switch (blockIdx.x) {
        case 0:
            for (int o = t; o < 16 * 28; o += 256) {
                int co = o / 28, j = o % 28;
                float v = 0.f;
                if (j < 27) {
                    float wv = w1[co * 27 + j];
                    v = (fabsf(wv) > delta) ? copysignf(alpha, wv) : 0.f;
                }
                tw1[o] = v;
            }
            break;
        case 1:
            for (int o = t; o < 4608; o += 256) {
                int co = o & 31;
                int k = (o >> 5) % 9;
                int ci = o / 288;
                float wv = w2[(co * 16 + ci) * 9 + k];
                tw2[o] = (fabsf(wv) > delta) ? copysignf(alpha, wv) : 0.f;
            }
            break;
        case 2:
            for (int o = t; o < 262144; o += 256) {
                int nn = o & 127;
                int k = o >> 7;
                float wv = wf1[(size_t)nn * 2048 + k];
                twf1[o] = (fabsf(wv) > delta) ? copysignf(alpha, wv) : 0.f;
            }
            break;
        default:
            for (int o = t; o < 1280; o += 256) {
                float wv = wf2[o];
                twf2[o] = (fabsf(wv) > delta) ? copysignf(alpha, wv) : 0.f;
            }
            break;
    }
}

// ---------------- fused conv1+pool+conv2+pool, one image per block ---------
__global__ __launch_bounds__(256, 2)
void conv12_kernel(const float* __restrict__ x,    // [B,3,32,32]
                   const float* __restrict__ b1,   // [16]
                   const float* __restrict__ b2,   // [32]
                   const float* __restrict__ tw1,  // [16][28]
                   const float* __restrict__ tw2,  // [16][9][32]
                   float* __restrict__ h2p) {      // [B,32,8,8]
    __shared__ float xs[3][34][34];    // 3468 f
    __shared__ float h1s[16][18][18];  // 5184 f
    __shared__ float w1s[16][28];      // 448 f
    __shared__ float w2s[16][9][32];   // 4608 f
    __shared__ float b1s[16], b2s[32];

    const int t = threadIdx.x;
    const int b = blockIdx.x;

    // zero (halos) + load weights
    {
        float* p = &xs[0][0][0];
        for (int i = t; i < 3468; i += 256) p[i] = 0.f;
        float* q = &h1s[0][0][0];
        for (int i = t; i < 5184; i += 256) q[i] = 0.f;
        for (int i = t; i < 448; i += 256) (&w1s[0][0])[i] = tw1[i];
        for (int i = t; i < 4608; i += 256) (&w2s[0][0][0])[i] = tw2[i];
        if (t < 16) b1s[t] = b1[t];
        if (t < 32) b2s[t] = b2[t];
    }
    __syncthreads();

    // load x interior
    {
        const float* xb = x + (size_t)b * 3072;
        for (int i = t; i < 3072; i += 256) {
            int c = i >> 10;
            int y = (i >> 5) & 31;
            int xx = i & 31;
            xs[c][y + 1][xx + 1] = xb[i];
        }
    }
    __syncthreads();

    // conv1 + relu + pool: thread -> pooled (py,px) in 16x16, all 16 co
    {
        const int py = t >> 4, px = t & 15;
        const int y0 = 2 * py, x0 = 2 * px;
        float patch[3][4][4];
#pragma unroll
        for (int c = 0; c < 3; ++c)
#pragma unroll
            for (int r = 0; r < 4; ++r)
#pragma unroll
                for (int cc = 0; cc < 4; ++cc)
                    patch[c][r][cc] = xs[c][y0 + r][x0 + cc];
#pragma unroll 1
        for (int co = 0; co < 16; ++co) {
            float w[27];
#pragma unroll
            for (int j = 0; j < 27; ++j) w[j] = w1s[co][j];
            const float bias = b1s[co];
            float m = 0.f;  // relu floor
#pragma unroll
            for (int dy = 0; dy < 2; ++dy)
#pragma unroll
                for (int dx = 0; dx < 2; ++dx) {
                    float acc = bias;
#pragma unroll
                    for (int c = 0; c < 3; ++c)
#pragma unroll
                        for (int ky = 0; ky < 3; ++ky)
#pragma unroll
                            for (int kx = 0; kx < 3; ++kx)
                                acc += patch[c][dy + ky][dx + kx] * w[(c * 3 + ky) * 3 + kx];
                    m = fmaxf(m, acc);
                }
            h1s[co][py + 1][px + 1] = m;
        }
    }
    __syncthreads();

    // conv2 + relu + pool: thread -> pooled (py,px) in 8x8, 8 co
    {
        const int s = t & 63;
        const int py = s >> 3, px = s & 7;
        const int cob = (t >> 6) << 3;  // 0,8,16,24
        const int y0 = 2 * py, x0 = 2 * px;
        float acc[8][2][2];
#pragma unroll
        for (int i = 0; i < 8; ++i) {
            const float bv = b2s[cob + i];
            acc[i][0][0] = bv; acc[i][0][1] = bv; acc[i][1][0] = bv; acc[i][1][1] = bv;
        }
#pragma unroll 1
        for (int ci = 0; ci < 16; ++ci) {
            float patch[4][4];
#pragma unroll
            for (int r = 0; r < 4; ++r)
#pragma unroll
                for (int cc = 0; cc < 4; ++cc)
                    patch[r][cc] = h1s[ci][y0 + r][x0 + cc];
#pragma unroll
            for (int ky = 0; ky < 3; ++ky)
#pragma unroll
                for (int kx = 0; kx < 3; ++kx) {
                    const int k = ky * 3 + kx;
                    float wv[8];
#pragma unroll
                    for (int i = 0; i < 8; ++i) wv[i] = w2s[ci][k][cob + i];
#pragma unroll
                    for (int i = 0; i < 8; ++i) {
                        acc[i][0][0] += patch[0 + ky][0 + kx] * wv[i];
                        acc[i][0][1] += patch[0 + ky][1 + kx] * wv[i];
                        acc[i][1][0] += patch[1 + ky][0 + kx] * wv[i];
                        acc[i][1][1] += patch[1 + ky][1 + kx] * wv[i];
                    }
                }
        }
        float* outp = h2p + (size_t)b * 2048;
#pragma unroll
        for (int i = 0; i < 8; ++i) {
            float m = fmaxf(fmaxf(acc[i][0][0], acc[i][0][1]),
                            fmaxf(acc[i][1][0], acc[i][1][1]));
            m = fmaxf(m, 0.f);
            outp[(cob + i) * 64 + py * 8 + px] = m;
        }
    }
}

// ---------------- fc1 (tiled GEMM) + relu + fc2 fused ----------------------
__global__ __launch_bounds__(256, 2)
void fc_kernel(const float* __restrict__ h2p,   // [B,2048]
               const float* __restrict__ twf1,  // [2048,128] (k-major)
               const float* __restrict__ bf1,   // [128]
               const float* __restrict__ twf2,  // [10,128]
               const float* __restrict__ bf2,   // [10]
               float* __restrict__ out) {       // [B,10]
    __shared__ float As[16][64];    // 1024 f
    __shared__ float Bs[64][128];   // 8192 f
    __shared__ float Hs[16][128];   // 2048 f
    const int t = threadIdx.x;
    const int m0 = blockIdx.x * 16;

    const int tm = t >> 5;   // 0..7
    const int tn = t & 31;   // 0..31
    float acc[2][4];
#pragma unroll
    for (int i = 0; i < 2; ++i)
#pragma unroll
        for (int j = 0; j < 4; ++j) acc[i][j] = 0.f;

    for (int k0 = 0; k0 < 2048; k0 += 64) {
        // A tile: 16x64, one float4/thread
        {
            int row = t >> 4;
            int col = (t & 15) << 2;
            const float4 v = *reinterpret_cast<const float4*>(
                &h2p[(size_t)(m0 + row) * 2048 + k0 + col]);
            *reinterpret_cast<float4*>(&As[row][col]) = v;
        }
        // B tile: 64x128 contiguous, 8 float4/thread
        {
            const float4* src = reinterpret_cast<const float4*>(&twf1[(size_t)k0 * 128]);
            float4* dst = reinterpret_cast<float4*>(&Bs[0][0]);
#pragma unroll
            for (int j = 0; j < 8; ++j) dst[t + j * 256] = src[t + j * 256];
        }
        __syncthreads();
#pragma unroll 4
        for (int kk = 0; kk < 64; ++kk) {
            const float a0 = As[tm * 2][kk];
            const float a1 = As[tm * 2 + 1][kk];
            const float4 bv = *reinterpret_cast<const float4*>(&Bs[kk][tn << 2]);
            acc[0][0] += a0 * bv.x; acc[0][1] += a0 * bv.y;
            acc[0][2] += a0 * bv.z; acc[0][3] += a0 * bv.w;
            acc[1][0] += a1 * bv.x; acc[1][1] += a1 * bv.y;
            acc[1][2] += a1 * bv.z; acc[1][3] += a1 * bv.w;
        }
        __syncthreads();
    }
    // bias + relu -> Hs
#pragma unroll
    for (int i = 0; i < 2; ++i) {
        const int m = tm * 2 + i;
#pragma unroll
        for (int j = 0; j < 4; ++j) {
            const int nn = (tn << 2) + j;
            Hs[m][nn] = fmaxf(acc[i][j] + bf1[nn], 0.f);
        }
    }
    __syncthreads();
    // fc2: 16 rows x 10 outs = 160 threads
    if (t < 160) {
        const int m = t / 10, nn = t % 10;
        float a = bf2[nn];
#pragma unroll 8
        for (int k = 0; k < 128; ++k) a += Hs[m][k] * twf2[nn * 128 + k];
        out[(size_t)(m0 + m) * 10 + nn] = a;
    }
}

// ---------------------------------------------------------------------------
extern "C" void kernel_launch(void* const* d_in, const int* in_sizes, int n_in,
                              void* d_out, int out_size, void* d_ws, size_t ws_size,
                              hipStream_t stream) {
    const float* x   = (const float*)d_in[0];
    const float* w1  = (const float*)d_in[1];
    const float* b1  = (const float*)d_in[2];
    const float* w2  = (const float*)d_in[3];
    const float* b2  = (const float*)d_in[4];
    const float* wf1 = (const float*)d_in[5];
    const float* bf1 = (const float*)d_in[6];
    const float* wf2 = (const float*)d_in[7];
    const float* bf2 = (const float*)d_in[8];
    float* out = (float*)d_out;
    const int B = in_sizes[0] / (3 * 32 * 32);  // 4096

    float* ws = (float*)d_ws;
    float* tw1  = ws;                           // 448
    float* tw2  = ws + 448;                     // 4608
    float* twf1 = ws + 448 + 4608;              // 262144
    float* twf2 = ws + 448 + 4608 + 262144;     // 1280
    float* h2p  = ws + 268480;                  // B*2048

    ternarize_all<<<4, 256, 0, stream>>>(w1, w2, wf1, wf2, tw1, tw2, twf1, twf2);
    conv12_kernel<<<B, 256, 0, stream>>>(x, b1, b2, tw1, tw2, h2p);
    fc_kernel<<<B / 16, 256, 0, stream>>>(h2p, twf1, bf1, twf2, bf2, out);
}

// Round 2
// 284.962 us; speedup vs baseline: 2.5781x; 2.5781x over previous
//
#include <hip/hip_runtime.h>
#include <math.h>

// ---------------------------------------------------------------------------
// SimpleTernaryNet forward:
//   tern(w) -> conv3x3(3->16)+b+relu -> maxpool2
//           -> conv3x3(16->32)+b+relu -> maxpool2
//           -> fc(2048->128)+b+relu -> fc(128->10)+b
// All fp32. B = 4096.
//
// ws layout (floats):
//   [0)        tw1   448    (16x28 padded)
//   [448)      tw2   4608   (ci16 x k9 x co32)
//   [5056)     twf1  262144 (k2048 x n128, transposed)
//   [267200)   twf2  1280   (10x128)
//   [268480)   h2p   B*2048
//   [268480+B*2048) partials: sum[64], sa[64], cnt[64]
// ---------------------------------------------------------------------------

#define WF1_N 262144
#define WF1_SLICES 64
#define WF1_SLICE 4096  // floats per slice

__device__ __forceinline__ float block_reduce_256(float v, float* red, int t) {
    red[t] = v; __syncthreads();
    for (int o = 128; o > 0; o >>= 1) {
        if (t < o) red[t] += red[t + o];
        __syncthreads();
    }
    float r = red[0]; __syncthreads();
    return r;
}

// ---------------- stage A: wf1 partial |sum| + small tensors complete ------
__global__ void tern_stageA(const float* __restrict__ w1,
                            const float* __restrict__ w2,
                            const float* __restrict__ wf1,
                            const float* __restrict__ wf2,
                            float* __restrict__ tw1,
                            float* __restrict__ tw2,
                            float* __restrict__ twf2,
                            float* __restrict__ part_sum) {
    __shared__ float red[256];
    const int t = threadIdx.x;
    const int bid = blockIdx.x;

    if (bid < WF1_SLICES) {
        // partial sum |wf1| over slice of 4096 floats, float4 coalesced
        const float4* src = reinterpret_cast<const float4*>(wf1 + (size_t)bid * WF1_SLICE);
        float s = 0.f;
#pragma unroll
        for (int j = 0; j < 4; ++j) {
            const float4 v = src[t + j * 256];
            s += fabsf(v.x) + fabsf(v.y) + fabsf(v.z) + fabsf(v.w);
        }
        const float tot = block_reduce_256(s, red, t);
        if (t == 0) part_sum[bid] = tot;
        return;
    }

    // small tensors: full ternarize in one block each
    const float* w;
    int n;
    const int which = bid - WF1_SLICES;  // 0:w1 1:w2 2:wf2
    switch (which) {
        case 0: w = w1;  n = 432;  break;
        case 1: w = w2;  n = 4608; break;
        default: w = wf2; n = 1280; break;
    }
    float s = 0.f;
    for (int i = t; i < n; i += 256) s += fabsf(w[i]);
    const float delta = 0.7f * block_reduce_256(s, red, t) / (float)n;
    float sa = 0.f, cnt = 0.f;
    for (int i = t; i < n; i += 256) {
        float a = fabsf(w[i]);
        if (a > delta) { sa += a; cnt += 1.f; }
    }
    const float tot_sa = block_reduce_256(sa, red, t);
    const float tot_cnt = block_reduce_256(cnt, red, t);
    const float alpha = tot_sa / fmaxf(tot_cnt, 1.0f);

    switch (which) {
        case 0:
            for (int o = t; o < 16 * 28; o += 256) {
                int co = o / 28, j = o % 28;
                float v = 0.f;
                if (j < 27) {
                    float wv = w1[co * 27 + j];
                    v = (fabsf(wv) > delta) ? copysignf(alpha, wv) : 0.f;
                }
                tw1[o] = v;
            }
            break;
        case 1:
            for (int o = t; o < 4608; o += 256) {
                int co = o & 31;
                int k = (o >> 5) % 9;
                int ci = o / 288;
                float wv = w2[(co * 16 + ci) * 9 + k];
                tw2[o] = (fabsf(wv) > delta) ? copysignf(alpha, wv) : 0.f;
            }
            break;
        default:
            for (int o = t; o < 1280; o += 256) {
                float wv = wf2[o];
                twf2[o] = (fabsf(wv) > delta) ? copysignf(alpha, wv) : 0.f;
            }
            break;
    }
}

// ---------------- stage B: delta (redundant) + masked partials -------------
__global__ void tern_stageB(const float* __restrict__ wf1,
                            const float* __restrict__ part_sum,
                            float* __restrict__ part_sa,
                            float* __restrict__ part_cnt) {
    __shared__ float red[256];
    const int t = threadIdx.x;
    const int bid = blockIdx.x;

    float v = (t < WF1_SLICES) ? part_sum[t] : 0.f;
    const float delta = 0.7f * block_reduce_256(v, red, t) / (float)WF1_N;

    const float4* src = reinterpret_cast<const float4*>(wf1 + (size_t)bid * WF1_SLICE);
    float sa = 0.f, cnt = 0.f;
#pragma unroll
    for (int j = 0; j < 4; ++j) {
        const float4 w4 = src[t + j * 256];
        float a;
        a = fabsf(w4.x); if (a > delta) { sa += a; cnt += 1.f; }
        a = fabsf(w4.y); if (a > delta) { sa += a; cnt += 1.f; }
        a = fabsf(w4.z); if (a > delta) { sa += a; cnt += 1.f; }
        a = fabsf(w4.w); if (a > delta) { sa += a; cnt += 1.f; }
    }
    const float tot_sa = block_reduce_256(sa, red, t);
    const float tot_cnt = block_reduce_256(cnt, red, t);
    if (t == 0) { part_sa[bid] = tot_sa; part_cnt[bid] = tot_cnt; }
}

// ---------------- stage C: alpha (redundant) + transposed ternary write ----
// wf1 [128 n][2048 k] -> twf1 [2048 k][128 n]; 32x32 tiles, 256 blocks.
__global__ void tern_stageC(const float* __restrict__ wf1,
                            const float* __restrict__ part_sum,
                            const float* __restrict__ part_sa,
                            const float* __restrict__ part_cnt,
                            float* __restrict__ twf1) {
    __shared__ float red[256];
    __shared__ float tile[32][33];
    const int t = threadIdx.x;
    const int bid = blockIdx.x;

    float v = (t < WF1_SLICES) ? part_sum[t] : 0.f;
    const float delta = 0.7f * block_reduce_256(v, red, t) / (float)WF1_N;
    v = (t < WF1_SLICES) ? part_sa[t] : 0.f;
    const float tot_sa = block_reduce_256(v, red, t);
    v = (t < WF1_SLICES) ? part_cnt[t] : 0.f;
    const float tot_cnt = block_reduce_256(v, red, t);
    const float alpha = tot_sa / fmaxf(tot_cnt, 1.0f);

    const int tn0 = (bid & 3) * 32;    // n-tile base (row of wf1)
    const int tk0 = (bid >> 2) * 32;   // k-tile base (col of wf1)

    // load + ternarize into LDS tile[n_local][k_local]
#pragma unroll
    for (int p = 0; p < 4; ++p) {
        const int r = p * 8 + (t >> 5);  // n_local
        const int c = t & 31;            // k_local
        const float wv = wf1[(size_t)(tn0 + r) * 2048 + tk0 + c];
        tile[r][c] = (fabsf(wv) > delta) ? copysignf(alpha, wv) : 0.f;
    }
    __syncthreads();

    // store transposed: twf1[k][n]
#pragma unroll
    for (int p = 0; p < 4; ++p) {
        const int rr = p * 8 + (t >> 5); // k_local
        const int cc = t & 31;           // n_local
        twf1[(size_t)(tk0 + rr) * 128 + tn0 + cc] = tile[cc][rr];
    }
}

// ---------------- fused conv1+pool+conv2+pool, one image per block ---------
__global__ __launch_bounds__(256, 2)
void conv12_kernel(const float* __restrict__ x,    // [B,3,32,32]
                   const float* __restrict__ b1,   // [16]
                   const float* __restrict__ b2,   // [32]
                   const float* __restrict__ tw1,  // [16][28]
                   const float* __restrict__ tw2,  // [16][9][32]
                   float* __restrict__ h2p) {      // [B,32,8,8]
    __shared__ float xs[3][34][34];    // 3468 f
    __shared__ float h1s[16][18][18];  // 5184 f
    __shared__ float w1s[16][28];      // 448 f
    __shared__ float w2s[16][9][32];   // 4608 f
    __shared__ float b1s[16], b2s[32];

    const int t = threadIdx.x;
    const int b = blockIdx.x;

    // zero (halos) + load weights
    {
        float* p = &xs[0][0][0];
        for (int i = t; i < 3468; i += 256) p[i] = 0.f;
        float* q = &h1s[0][0][0];
        for (int i = t; i < 5184; i += 256) q[i] = 0.f;
        for (int i = t; i < 448; i += 256) (&w1s[0][0])[i] = tw1[i];
        for (int i = t; i < 4608; i += 256) (&w2s[0][0][0])[i] = tw2[i];
        if (t < 16) b1s[t] = b1[t];
        if (t < 32) b2s[t] = b2[t];
    }
    __syncthreads();

    // load x interior
    {
        const float* xb = x + (size_t)b * 3072;
        for (int i = t; i < 3072; i += 256) {
            int c = i >> 10;
            int y = (i >> 5) & 31;
            int xx = i & 31;
            xs[c][y + 1][xx + 1] = xb[i];
        }
    }
    __syncthreads();

    // conv1 + relu + pool: thread -> pooled (py,px) in 16x16, all 16 co
    {
        const int py = t >> 4, px = t & 15;
        const int y0 = 2 * py, x0 = 2 * px;
        float patch[3][4][4];
#pragma unroll
        for (int c = 0; c < 3; ++c)
#pragma unroll
            for (int r = 0; r < 4; ++r)
#pragma unroll
                for (int cc = 0; cc < 4; ++cc)
                    patch[c][r][cc] = xs[c][y0 + r][x0 + cc];
#pragma unroll 1
        for (int co = 0; co < 16; ++co) {
            float w[27];
#pragma unroll
            for (int j = 0; j < 27; ++j) w[j] = w1s[co][j];
            const float bias = b1s[co];
            float m = 0.f;  // relu floor
#pragma unroll
            for (int dy = 0; dy < 2; ++dy)
#pragma unroll
                for (int dx = 0; dx < 2; ++dx) {
                    float acc = bias;
#pragma unroll
                    for (int c = 0; c < 3; ++c)
#pragma unroll
                        for (int ky = 0; ky < 3; ++ky)
#pragma unroll
                            for (int kx = 0; kx < 3; ++kx)
                                acc += patch[c][dy + ky][dx + kx] * w[(c * 3 + ky) * 3 + kx];
                    m = fmaxf(m, acc);
                }
            h1s[co][py + 1][px + 1] = m;
        }
    }
    __syncthreads();

    // conv2 + relu + pool: thread -> pooled (py,px) in 8x8, 8 co
    {
        const int s = t & 63;
        const int py = s >> 3, px = s & 7;
        const int cob = (t >> 6) << 3;  // 0,8,16,24
        const int y0 = 2 * py, x0 = 2 * px;
        float acc[8][2][2];
#pragma unroll
        for (int i = 0; i < 8; ++i) {
            const float bv = b2s[cob + i];
            acc[i][0][0] = bv; acc[i][0][1] = bv; acc[i][1][0] = bv; acc[i][1][1] = bv;
        }
#pragma unroll 1
        for (int ci = 0; ci < 16; ++ci) {
            float patch[4][4];
#pragma unroll
            for (int r = 0; r < 4; ++r)
#pragma unroll
                for (int cc = 0; cc < 4; ++cc)
                    patch[r][cc] = h1s[ci][y0 + r][x0 + cc];
#pragma unroll
            for (int ky = 0; ky < 3; ++ky)
#pragma unroll
                for (int kx = 0; kx < 3; ++kx) {
                    const int k = ky * 3 + kx;
                    float wv[8];
#pragma unroll
                    for (int i = 0; i < 8; ++i) wv[i] = w2s[ci][k][cob + i];
#pragma unroll
                    for (int i = 0; i < 8; ++i) {
                        acc[i][0][0] += patch[0 + ky][0 + kx] * wv[i];
                        acc[i][0][1] += patch[0 + ky][1 + kx] * wv[i];
                        acc[i][1][0] += patch[1 + ky][0 + kx] * wv[i];
                        acc[i][1][1] += patch[1 + ky][1 + kx] * wv[i];
                    }
                }
        }
        float* outp = h2p + (size_t)b * 2048;
#pragma unroll
        for (int i = 0; i < 8; ++i) {
            float m = fmaxf(fmaxf(acc[i][0][0], acc[i][0][1]),
                            fmaxf(acc[i][1][0], acc[i][1][1]));
            m = fmaxf(m, 0.f);
            outp[(cob + i) * 64 + py * 8 + px] = m;
        }
    }
}

// ---------------- fc1 (tiled GEMM) + relu + fc2 fused ----------------------
__global__ __launch_bounds__(256, 2)
void fc_kernel(const float* __restrict__ h2p,   // [B,2048]
               const float* __restrict__ twf1,  // [2048,128] (k-major)
               const float* __restrict__ bf1,   // [128]
               const float* __restrict__ twf2,  // [10,128]
               const float* __restrict__ bf2,   // [10]
               float* __restrict__ out) {       // [B,10]
    __shared__ float As[16][64];    // 1024 f
    __shared__ float Bs[64][128];   // 8192 f
    __shared__ float Hs[16][128];   // 2048 f
    const int t = threadIdx.x;
    const int m0 = blockIdx.x * 16;

    const int tm = t >> 5;   // 0..7
    const int tn = t & 31;   // 0..31
    float acc[2][4];
#pragma unroll
    for (int i = 0; i < 2; ++i)
#pragma unroll
        for (int j = 0; j < 4; ++j) acc[i][j] = 0.f;

    for (int k0 = 0; k0 < 2048; k0 += 64) {
        // A tile: 16x64, one float4/thread
        {
            int row = t >> 4;
            int col = (t & 15) << 2;
            const float4 v = *reinterpret_cast<const float4*>(
                &h2p[(size_t)(m0 + row) * 2048 + k0 + col]);
            *reinterpret_cast<float4*>(&As[row][col]) = v;
        }
        // B tile: 64x128 contiguous, 8 float4/thread
        {
            const float4* src = reinterpret_cast<const float4*>(&twf1[(size_t)k0 * 128]);
            float4* dst = reinterpret_cast<float4*>(&Bs[0][0]);
#pragma unroll
            for (int j = 0; j < 8; ++j) dst[t + j * 256] = src[t + j * 256];
        }
        __syncthreads();
#pragma unroll 4
        for (int kk = 0; kk < 64; ++kk) {
            const float a0 = As[tm * 2][kk];
            const float a1 = As[tm * 2 + 1][kk];
            const float4 bv = *reinterpret_cast<const float4*>(&Bs[kk][tn << 2]);
            acc[0][0] += a0 * bv.x; acc[0][1] += a0 * bv.y;
            acc[0][2] += a0 * bv.z; acc[0][3] += a0 * bv.w;
            acc[1][0] += a1 * bv.x; acc[1][1] += a1 * bv.y;
            acc[1][2] += a1 * bv.z; acc[1][3] += a1 * bv.w;
        }
        __syncthreads();
    }
    // bias + relu -> Hs
#pragma unroll
    for (int i = 0; i < 2; ++i) {
        const int m = tm * 2 + i;
#pragma unroll
        for (int j = 0; j < 4; ++j) {
            const int nn = (tn << 2) + j;
            Hs[m][nn] = fmaxf(acc[i][j] + bf1[nn], 0.f);
        }
    }
    __syncthreads();
    // fc2: 16 rows x 10 outs = 160 threads
    if (t < 160) {
        const int m = t / 10, nn = t % 10;
        float a = bf2[nn];
#pragma unroll 8
        for (int k = 0; k < 128; ++k) a += Hs[m][k] * twf2[nn * 128 + k];
        out[(size_t)(m0 + m) * 10 + nn] = a;
    }
}

// ---------------------------------------------------------------------------
extern "C" void kernel_launch(void* const* d_in, const int* in_sizes, int n_in,
                              void* d_out, int out_size, void* d_ws, size_t ws_size,
                              hipStream_t stream) {
    const float* x   = (const float*)d_in[0];
    const float* w1  = (const float*)d_in[1];
    const float* b1  = (const float*)d_in[2];
    const float* w2  = (const float*)d_in[3];
    const float* b2  = (const float*)d_in[4];
    const float* wf1 = (const float*)d_in[5];
    const float* bf1 = (const float*)d_in[6];
    const float* wf2 = (const float*)d_in[7];
    const float* bf2 = (const float*)d_in[8];
    float* out = (float*)d_out;
    const int B = in_sizes[0] / (3 * 32 * 32);  // 4096

    float* ws = (float*)d_ws;
    float* tw1  = ws;                           // 448
    float* tw2  = ws + 448;                     // 4608
    float* twf1 = ws + 5056;                    // 262144
    float* twf2 = ws + 267200;                  // 1280
    float* h2p  = ws + 268480;                  // B*2048
    float* part_sum = h2p + (size_t)B * 2048;   // 64
    float* part_sa  = part_sum + 64;            // 64
    float* part_cnt = part_sa + 64;             // 64

    tern_stageA<<<WF1_SLICES + 3, 256, 0, stream>>>(w1, w2, wf1, wf2,
                                                    tw1, tw2, twf2, part_sum);
    tern_stageB<<<WF1_SLICES, 256, 0, stream>>>(wf1, part_sum, part_sa, part_cnt);
    tern_stageC<<<256, 256, 0, stream>>>(wf1, part_sum, part_sa, part_cnt, twf1);
    conv12_kernel<<<B, 256, 0, stream>>>(x, b1, b2, tw1, tw2, h2p);
    fc_kernel<<<B / 16, 256, 0, stream>>>(h2p, twf1, bf1, twf2, bf2, out);
}

// Round 3
// 154.684 us; speedup vs baseline: 4.7493x; 1.8422x over previous
//
#include <hip/hip_runtime.h>
#include <math.h>

// ---------------------------------------------------------------------------
// SimpleTernaryNet forward, MFMA-f16 for conv2 + fc1.
//   tern(w) -> conv3x3(3->16)+b+relu -> maxpool2      (fp32 VALU)
//           -> conv3x3(16->32)+b+relu -> maxpool2     (f16 MFMA, 9-shift)
//           -> fc(2048->128)+b+relu                   (f16 MFMA)
//           -> fc(128->10)+b                          (fp32 VALU)
//
// ws layout (bytes):
//   [0)         tw1    f32 [16][28]                  1792 B
//   [1792)      tw2f   f16 [9][2][64][4] (B-frags)   9216 B
//   [11008)     twf1   f16 [128 n][2048 k]           524288 B
//   [535296)    twf2   f32 [10][128]                 5120 B
//   [540416)    h2p    f16 [4096][2048]              16777216 B
//   [17317632)  partials f32 sum[64], sa[64], cnt[64]
// ---------------------------------------------------------------------------

typedef _Float16 half2v __attribute__((ext_vector_type(2)));
typedef _Float16 half4  __attribute__((ext_vector_type(4)));
typedef _Float16 half8  __attribute__((ext_vector_type(8)));
typedef float    f32x4  __attribute__((ext_vector_type(4)));

#define WF1_N 262144
#define WF1_SLICES 64
#define WF1_SLICE 4096

__device__ __forceinline__ float block_reduce_256(float v, float* red, int t) {
    red[t] = v; __syncthreads();
    for (int o = 128; o > 0; o >>= 1) {
        if (t < o) red[t] += red[t + o];
        __syncthreads();
    }
    float r = red[0]; __syncthreads();
    return r;
}

__device__ __forceinline__ unsigned pk16(float a, float b) {
    half2v h;
    h[0] = (_Float16)a;
    h[1] = (_Float16)b;
    return __builtin_bit_cast(unsigned, h);
}

// ---------------- stage A: wf1 partial |sum| + small tensors complete ------
__global__ void tern_stageA(const float* __restrict__ w1,
                            const float* __restrict__ w2,
                            const float* __restrict__ wf1,
                            const float* __restrict__ wf2,
                            float* __restrict__ tw1,
                            _Float16* __restrict__ tw2f,
                            float* __restrict__ twf2,
                            float* __restrict__ part_sum) {
    __shared__ float red[256];
    const int t = threadIdx.x;
    const int bid = blockIdx.x;

    if (bid < WF1_SLICES) {
        const float4* src = reinterpret_cast<const float4*>(wf1 + (size_t)bid * WF1_SLICE);
        float s = 0.f;
#pragma unroll
        for (int j = 0; j < 4; ++j) {
            const float4 v = src[t + j * 256];
            s += fabsf(v.x) + fabsf(v.y) + fabsf(v.z) + fabsf(v.w);
        }
        const float tot = block_reduce_256(s, red, t);
        if (t == 0) part_sum[bid] = tot;
        return;
    }

    const float* w;
    int n;
    const int which = bid - WF1_SLICES;  // 0:w1 1:w2 2:wf2
    switch (which) {
        case 0: w = w1;  n = 432;  break;
        case 1: w = w2;  n = 4608; break;
        default: w = wf2; n = 1280; break;
    }
    float s = 0.f;
    for (int i = t; i < n; i += 256) s += fabsf(w[i]);
    const float delta = 0.7f * block_reduce_256(s, red, t) / (float)n;
    float sa = 0.f, cnt = 0.f;
    for (int i = t; i < n; i += 256) {
        float a = fabsf(w[i]);
        if (a > delta) { sa += a; cnt += 1.f; }
    }
    const float tot_sa = block_reduce_256(sa, red, t);
    const float tot_cnt = block_reduce_256(cnt, red, t);
    const float alpha = tot_sa / fmaxf(tot_cnt, 1.0f);

    switch (which) {
        case 0:
            for (int o = t; o < 16 * 28; o += 256) {
                int co = o / 28, j = o % 28;
                float v = 0.f;
                if (j < 27) {
                    float wv = w1[co * 27 + j];
                    v = (fabsf(wv) > delta) ? copysignf(alpha, wv) : 0.f;
                }
                tw1[o] = v;
            }
            break;
        case 1:
            // B-fragment layout for 16x16x16 f16 MFMA:
            // o = ((s*2+nt)*64 + lane)*4 + j ; ci=(lane>>4)*4+j ; co=(lane&15)+nt*16
            for (int o = t; o < 4608; o += 256) {
                int j  = o & 3;
                int ll = (o >> 2) & 63;
                int nt = (o >> 8) & 1;
                int s9 = o >> 9;
                int ci = (ll >> 4) * 4 + j;
                int co = (ll & 15) + nt * 16;
                float wv = w2[(co * 16 + ci) * 9 + s9];
                float v = (fabsf(wv) > delta) ? copysignf(alpha, wv) : 0.f;
                tw2f[o] = (_Float16)v;
            }
            break;
        default:
            for (int o = t; o < 1280; o += 256) {
                float wv = wf2[o];
                twf2[o] = (fabsf(wv) > delta) ? copysignf(alpha, wv) : 0.f;
            }
            break;
    }
}

// ---------------- stage B: delta (redundant) + masked partials -------------
__global__ void tern_stageB(const float* __restrict__ wf1,
                            const float* __restrict__ part_sum,
                            float* __restrict__ part_sa,
                            float* __restrict__ part_cnt) {
    __shared__ float red[256];
    const int t = threadIdx.x;
    const int bid = blockIdx.x;

    float v = (t < WF1_SLICES) ? part_sum[t] : 0.f;
    const float delta = 0.7f * block_reduce_256(v, red, t) / (float)WF1_N;

    const float4* src = reinterpret_cast<const float4*>(wf1 + (size_t)bid * WF1_SLICE);
    float sa = 0.f, cnt = 0.f;
#pragma unroll
    for (int j = 0; j < 4; ++j) {
        const float4 w4 = src[t + j * 256];
        float a;
        a = fabsf(w4.x); if (a > delta) { sa += a; cnt += 1.f; }
        a = fabsf(w4.y); if (a > delta) { sa += a; cnt += 1.f; }
        a = fabsf(w4.z); if (a > delta) { sa += a; cnt += 1.f; }
        a = fabsf(w4.w); if (a > delta) { sa += a; cnt += 1.f; }
    }
    const float tot_sa = block_reduce_256(sa, red, t);
    const float tot_cnt = block_reduce_256(cnt, red, t);
    if (t == 0) { part_sa[bid] = tot_sa; part_cnt[bid] = tot_cnt; }
}

// ---------------- stage C: alpha (redundant) + f16 ternary write -----------
// twf1 keeps wf1's native [n=128][k=2048] orientation (no transpose).
__global__ void tern_stageC(const float* __restrict__ wf1,
                            const float* __restrict__ part_sum,
                            const float* __restrict__ part_sa,
                            const float* __restrict__ part_cnt,
                            _Float16* __restrict__ twf1) {
    __shared__ float red[256];
    const int t = threadIdx.x;

    float v = (t < WF1_SLICES) ? part_sum[t] : 0.f;
    const float delta = 0.7f * block_reduce_256(v, red, t) / (float)WF1_N;
    v = (t < WF1_SLICES) ? part_sa[t] : 0.f;
    const float tot_sa = block_reduce_256(v, red, t);
    v = (t < WF1_SLICES) ? part_cnt[t] : 0.f;
    const float tot_cnt = block_reduce_256(v, red, t);
    const float alpha = tot_sa / fmaxf(tot_cnt, 1.0f);

    const int tid = blockIdx.x * 256 + t;  // 65536 threads x 4 elems
    const float4 w4 = reinterpret_cast<const float4*>(wf1)[tid];
    half4 hv;
    hv[0] = (_Float16)((fabsf(w4.x) > delta) ? copysignf(alpha, w4.x) : 0.f);
    hv[1] = (_Float16)((fabsf(w4.y) > delta) ? copysignf(alpha, w4.y) : 0.f);
    hv[2] = (_Float16)((fabsf(w4.z) > delta) ? copysignf(alpha, w4.z) : 0.f);
    hv[3] = (_Float16)((fabsf(w4.w) > delta) ? copysignf(alpha, w4.w) : 0.f);
    reinterpret_cast<half4*>(twf1)[tid] = hv;
}

// ---------------- fused conv1(fp32)+pool + conv2(MFMA f16)+pool ------------
#define H1P 20  // f16 per pixel slot (16 ci + 4 pad)

__global__ __launch_bounds__(256, 3)
void conv12_kernel(const float* __restrict__ x,      // [B,3,32,32]
                   const float* __restrict__ b1,     // [16]
                   const float* __restrict__ b2,     // [32]
                   const float* __restrict__ tw1,    // [16][28] f32
                   const _Float16* __restrict__ tw2f,// [9][2][64][4] f16 B-frags
                   _Float16* __restrict__ h2p) {     // [B,2048] f16
    __shared__ float xs[3][34][34];          // 13872 B
    __shared__ _Float16 h1s[18 * 18 * H1P];  // 12960 B, idx (y*18+x)*20+ci
    __shared__ float w1s[16][28];            // 1792 B
    __shared__ float b1s[16], b2s[32];
    __shared__ _Float16 h2s[2048];           // 4096 B, idx co*64+py*8+px

    const int t = threadIdx.x;
    const int b = blockIdx.x;

    // phase 0: zero + weights
    {
        float* p = &xs[0][0][0];
        for (int i = t; i < 3468; i += 256) p[i] = 0.f;
        unsigned* q = reinterpret_cast<unsigned*>(h1s);
        for (int i = t; i < 3240; i += 256) q[i] = 0u;
        for (int i = t; i < 448; i += 256) (&w1s[0][0])[i] = tw1[i];
        if (t < 16) b1s[t] = b1[t];
        if (t < 32) b2s[t] = b2[t];
    }
    __syncthreads();

    // x interior
    {
        const float* xb = x + (size_t)b * 3072;
        for (int i = t; i < 3072; i += 256) {
            int c = i >> 10;
            int y = (i >> 5) & 31;
            int xx = i & 31;
            xs[c][y + 1][xx + 1] = xb[i];
        }
    }
    __syncthreads();

    // conv1 + relu + pool (fp32): thread -> pooled (py,px), all 16 co
    {
        const int py = t >> 4, px = t & 15;
        const int y0 = 2 * py, x0 = 2 * px;
        float patch[3][4][4];
#pragma unroll
        for (int c = 0; c < 3; ++c)
#pragma unroll
            for (int r = 0; r < 4; ++r)
#pragma unroll
                for (int cc = 0; cc < 4; ++cc)
                    patch[c][r][cc] = xs[c][y0 + r][x0 + cc];
        float mout[16];
#pragma unroll 1
        for (int co = 0; co < 16; ++co) {
            float w[27];
#pragma unroll
            for (int j = 0; j < 27; ++j) w[j] = w1s[co][j];
            const float bias = b1s[co];
            float m = 0.f;
#pragma unroll
            for (int dy = 0; dy < 2; ++dy)
#pragma unroll
                for (int dx = 0; dx < 2; ++dx) {
                    float acc = bias;
#pragma unroll
                    for (int c = 0; c < 3; ++c)
#pragma unroll
                        for (int ky = 0; ky < 3; ++ky)
#pragma unroll
                            for (int kx = 0; kx < 3; ++kx)
                                acc += patch[c][dy + ky][dx + kx] * w[(c * 3 + ky) * 3 + kx];
                    m = fmaxf(m, acc);
                }
            mout[co] = m;
        }
        // write h1 channel-last f16 at interior (py+1, px+1)
        const int pix = (py + 1) * 18 + (px + 1);
        unsigned* h1u = reinterpret_cast<unsigned*>(h1s);
#pragma unroll
        for (int c = 0; c < 8; ++c)
            h1u[pix * (H1P / 2) + c] = pk16(mout[2 * c], mout[2 * c + 1]);
    }

    // B fragments for conv2 (global, per-lane 8B, coalesced)
    const int l = t & 63;
    half4 bfr[9][2];
#pragma unroll
    for (int s = 0; s < 9; ++s)
#pragma unroll
        for (int nt = 0; nt < 2; ++nt)
            bfr[s][nt] = *reinterpret_cast<const half4*>(
                tw2f + (size_t)((s * 2 + nt) * 64 + l) * 4);
    __syncthreads();

    // conv2 (9-shift MFMA) + bias + relu + pool
    {
        const int wid = t >> 6;
        const int xq = l & 15, g = l >> 4;
        float sav[2][2];
#pragma unroll
        for (int yy = 0; yy < 4; ++yy) {
            const int y = wid * 4 + yy;
            f32x4 acc0 = {0.f, 0.f, 0.f, 0.f};
            f32x4 acc1 = {0.f, 0.f, 0.f, 0.f};
#pragma unroll
            for (int s = 0; s < 9; ++s) {
                const int dy = s / 3, dx = s % 3;
                const half4 a = *reinterpret_cast<const half4*>(
                    &h1s[((y + dy) * 18 + (xq + dx)) * H1P + g * 4]);
                acc0 = __builtin_amdgcn_mfma_f32_16x16x16f16(a, bfr[s][0], acc0, 0, 0, 0);
                acc1 = __builtin_amdgcn_mfma_f32_16x16x16f16(a, bfr[s][1], acc1, 0, 0, 0);
            }
            // x-pool: lane rows are pixels x = g*4 + r
            const float p00 = fmaxf(acc0[0], acc0[1]);
            const float p01 = fmaxf(acc0[2], acc0[3]);
            const float p10 = fmaxf(acc1[0], acc1[1]);
            const float p11 = fmaxf(acc1[2], acc1[3]);
            if ((yy & 1) == 0) {
                sav[0][0] = p00; sav[0][1] = p01;
                sav[1][0] = p10; sav[1][1] = p11;
            } else {
                const int py = (wid * 4 + yy) >> 1;
                const float v00 = fmaxf(fmaxf(sav[0][0], p00) + b2s[xq], 0.f);
                const float v01 = fmaxf(fmaxf(sav[0][1], p01) + b2s[xq], 0.f);
                const float v10 = fmaxf(fmaxf(sav[1][0], p10) + b2s[xq + 16], 0.f);
                const float v11 = fmaxf(fmaxf(sav[1][1], p11) + b2s[xq + 16], 0.f);
                unsigned* h2u = reinterpret_cast<unsigned*>(h2s);
                h2u[xq * 32 + py * 4 + g]        = pk16(v00, v01);
                h2u[(xq + 16) * 32 + py * 4 + g] = pk16(v10, v11);
            }
        }
    }
    __syncthreads();

    // h2s -> global (coalesced 16B/thread)
    {
        const float4 v = reinterpret_cast<const float4*>(h2s)[t];
        reinterpret_cast<float4*>(h2p + (size_t)b * 2048)[t] = v;
    }
}

// ---------------- fc1 (MFMA f16) + relu + fc2 (fp32) fused -----------------
__global__ __launch_bounds__(256, 2)
void fc_kernel(const _Float16* __restrict__ h2p,   // [B,2048]
               const _Float16* __restrict__ twf1,  // [128 n][2048 k]
               const float* __restrict__ bf1,      // [128]
               const float* __restrict__ twf2,     // [10][128]
               const float* __restrict__ bf2,      // [10]
               float* __restrict__ out) {          // [B,10]
    __shared__ _Float16 Al[4 * 64 * 8];   // 4096 B, fragment-ordered
    __shared__ _Float16 Bl[8 * 64 * 8];   // 8192 B, fragment-ordered
    __shared__ float Hs[64][132];         // 33792 B

    const int t = threadIdx.x;
    const int m0 = blockIdx.x * 64;
    const int wid = t >> 6, l = t & 63;
    const int lx = l & 15, g = l >> 4;

    f32x4 acc[8];
#pragma unroll
    for (int nt = 0; nt < 8; ++nt) acc[nt] = (f32x4){0.f, 0.f, 0.f, 0.f};

    for (int k0 = 0; k0 < 2048; k0 += 32) {
        // stage A fragments: entry t = (wave w, lane l)
        {
            const _Float16* src = h2p + (size_t)(m0 + wid * 16 + lx) * 2048 + k0 + g * 8;
            reinterpret_cast<float4*>(Al)[t] = *reinterpret_cast<const float4*>(src);
        }
        // stage B fragments: 512 entries, 2 per thread
        {
#pragma unroll
            for (int c = 0; c < 2; ++c) {
                const int e = t + c * 256;
                const int nt = e >> 6, el = e & 63;
                const _Float16* src = twf1 + (size_t)(nt * 16 + (el & 15)) * 2048 + k0 + (el >> 4) * 8;
                reinterpret_cast<float4*>(Bl)[e] = *reinterpret_cast<const float4*>(src);
            }
        }
        __syncthreads();
        const half8 a = reinterpret_cast<const half8*>(Al)[wid * 64 + l];
#pragma unroll
        for (int nt = 0; nt < 8; ++nt) {
            const half8 bb = reinterpret_cast<const half8*>(Bl)[nt * 64 + l];
            acc[nt] = __builtin_amdgcn_mfma_f32_16x16x32_f16(a, bb, acc[nt], 0, 0, 0);
        }
        __syncthreads();
    }

    // bias + relu -> Hs  (D: row = g*4+r within tile, col = lx + nt*16)
#pragma unroll
    for (int nt = 0; nt < 8; ++nt) {
        const int n = nt * 16 + lx;
        const float bias = bf1[n];
#pragma unroll
        for (int r = 0; r < 4; ++r)
            Hs[wid * 16 + g * 4 + r][n] = fmaxf(acc[nt][r] + bias, 0.f);
    }
    __syncthreads();

    // fc2: 640 outputs (64 rows x 10)
    for (int o = t; o < 640; o += 256) {
        const int m = o / 10, n = o % 10;
        float a = bf2[n];
#pragma unroll 8
        for (int k = 0; k < 128; ++k) a += Hs[m][k] * twf2[n * 128 + k];
        out[(size_t)(m0 + m) * 10 + n] = a;
    }
}

// ---------------------------------------------------------------------------
extern "C" void kernel_launch(void* const* d_in, const int* in_sizes, int n_in,
                              void* d_out, int out_size, void* d_ws, size_t ws_size,
                              hipStream_t stream) {
    const float* x   = (const float*)d_in[0];
    const float* w1  = (const float*)d_in[1];
    const float* b1  = (const float*)d_in[2];
    const float* w2  = (const float*)d_in[3];
    const float* b2  = (const float*)d_in[4];
    const float* wf1 = (const float*)d_in[5];
    const float* bf1 = (const float*)d_in[6];
    const float* wf2 = (const float*)d_in[7];
    const float* bf2 = (const float*)d_in[8];
    float* out = (float*)d_out;
    const int B = in_sizes[0] / (3 * 32 * 32);  // 4096

    char* ws = (char*)d_ws;
    float*     tw1   = (float*)(ws + 0);
    _Float16*  tw2f  = (_Float16*)(ws + 1792);
    _Float16*  twf1  = (_Float16*)(ws + 11008);
    float*     twf2  = (float*)(ws + 535296);
    _Float16*  h2p   = (_Float16*)(ws + 540416);
    float*     part_sum = (float*)(ws + 17317632);
    float*     part_sa  = part_sum + 64;
    float*     part_cnt = part_sa + 64;

    tern_stageA<<<WF1_SLICES + 3, 256, 0, stream>>>(w1, w2, wf1, wf2,
                                                    tw1, tw2f, twf2, part_sum);
    tern_stageB<<<WF1_SLICES, 256, 0, stream>>>(wf1, part_sum, part_sa, part_cnt);
    tern_stageC<<<256, 256, 0, stream>>>(wf1, part_sum, part_sa, part_cnt, twf1);
    conv12_kernel<<<B, 256, 0, stream>>>(x, b1, b2, tw1, tw2f, h2p);
    fc_kernel<<<B / 64, 256, 0, stream>>>(h2p, twf1, bf1, twf2, bf2, out);
}

// Round 4
// 117.408 us; speedup vs baseline: 6.2572x; 1.3175x over previous
//
#include <hip/hip_runtime.h>
#include <math.h>

// ---------------------------------------------------------------------------
// SimpleTernaryNet forward, MFMA-f16 for conv1 + conv2 + fc1.
//   tern(w) -> conv3x3(3->16)+b+relu -> maxpool2      (f16 MFMA, 9-row K=27)
//           -> conv3x3(16->32)+b+relu -> maxpool2     (f16 MFMA, 9-shift)
//           -> fc(2048->128)+b+relu                   (f16 MFMA)
//           -> fc(128->10)+b                          (fp32 VALU)
//
// ws layout (bytes):
//   [0)         tw1f   f16 [3][64][4] conv1 B-frags   1536 B
//   [1536)      tw2f   f16 [9][2][64][4] conv2 B-frags 9216 B
//   [10752)     twf1   f16 [128 n][2048 k]            524288 B
//   [535040)    twf2   f32 [10][128]                  5120 B
//   [540160)    h2p    f16 [4096][2048]               16777216 B
//   [17317376)  partials f32 sum[64], sa[64], cnt[64]
// ---------------------------------------------------------------------------

typedef _Float16 half2v __attribute__((ext_vector_type(2)));
typedef _Float16 half4  __attribute__((ext_vector_type(4)));
typedef _Float16 half8  __attribute__((ext_vector_type(8)));
typedef float    f32x4  __attribute__((ext_vector_type(4)));
typedef unsigned u32x2  __attribute__((ext_vector_type(2)));

#define WF1_N 262144
#define WF1_SLICES 64
#define WF1_SLICE 4096

__device__ __forceinline__ float block_reduce_256(float v, float* red, int t) {
    red[t] = v; __syncthreads();
    for (int o = 128; o > 0; o >>= 1) {
        if (t < o) red[t] += red[t + o];
        __syncthreads();
    }
    float r = red[0]; __syncthreads();
    return r;
}

__device__ __forceinline__ unsigned pk16(float a, float b) {
    half2v h;
    h[0] = (_Float16)a;
    h[1] = (_Float16)b;
    return __builtin_bit_cast(unsigned, h);
}

// ---------------- stage A: wf1 partial |sum| + small tensors complete ------
__global__ void tern_stageA(const float* __restrict__ w1,
                            const float* __restrict__ w2,
                            const float* __restrict__ wf1,
                            const float* __restrict__ wf2,
                            _Float16* __restrict__ tw1f,
                            _Float16* __restrict__ tw2f,
                            float* __restrict__ twf2,
                            float* __restrict__ part_sum) {
    __shared__ float red[256];
    const int t = threadIdx.x;
    const int bid = blockIdx.x;

    if (bid < WF1_SLICES) {
        const float4* src = reinterpret_cast<const float4*>(wf1 + (size_t)bid * WF1_SLICE);
        float s = 0.f;
#pragma unroll
        for (int j = 0; j < 4; ++j) {
            const float4 v = src[t + j * 256];
            s += fabsf(v.x) + fabsf(v.y) + fabsf(v.z) + fabsf(v.w);
        }
        const float tot = block_reduce_256(s, red, t);
        if (t == 0) part_sum[bid] = tot;
        return;
    }

    const float* w;
    int n;
    const int which = bid - WF1_SLICES;  // 0:w1 1:w2 2:wf2
    switch (which) {
        case 0: w = w1;  n = 432;  break;
        case 1: w = w2;  n = 4608; break;
        default: w = wf2; n = 1280; break;
    }
    float s = 0.f;
    for (int i = t; i < n; i += 256) s += fabsf(w[i]);
    const float delta = 0.7f * block_reduce_256(s, red, t) / (float)n;
    float sa = 0.f, cnt = 0.f;
    for (int i = t; i < n; i += 256) {
        float a = fabsf(w[i]);
        if (a > delta) { sa += a; cnt += 1.f; }
    }
    const float tot_sa = block_reduce_256(sa, red, t);
    const float tot_cnt = block_reduce_256(cnt, red, t);
    const float alpha = tot_sa / fmaxf(tot_cnt, 1.0f);

    switch (which) {
        case 0:
            // conv1 B-frags: 3 MFMAs (K-rows rho=m*4+g, rho=(c,ky)), taps j=0..2.
            // entry o = (m*64 + l)*4 + j ; co = l&15 ; rho = m*4 + (l>>4)
            for (int o = t; o < 768; o += 256) {
                int j = o & 3;
                int l = (o >> 2) & 63;
                int m = o >> 8;
                int rho = m * 4 + (l >> 4);
                int co = l & 15;
                float v = 0.f;
                if (rho < 9 && j < 3) {
                    float wv = w1[co * 27 + (rho / 3) * 9 + (rho % 3) * 3 + j];
                    v = (fabsf(wv) > delta) ? copysignf(alpha, wv) : 0.f;
                }
                tw1f[o] = (_Float16)v;
            }
            break;
        case 1:
            // conv2 B-frags for 16x16x16 f16 MFMA:
            // o = ((s*2+nt)*64 + lane)*4 + j ; ci=(lane>>4)*4+j ; co=(lane&15)+nt*16
            for (int o = t; o < 4608; o += 256) {
                int j  = o & 3;
                int ll = (o >> 2) & 63;
                int nt = (o >> 8) & 1;
                int s9 = o >> 9;
                int ci = (ll >> 4) * 4 + j;
                int co = (ll & 15) + nt * 16;
                float wv = w2[(co * 16 + ci) * 9 + s9];
                float v = (fabsf(wv) > delta) ? copysignf(alpha, wv) : 0.f;
                tw2f[o] = (_Float16)v;
            }
            break;
        default:
            for (int o = t; o < 1280; o += 256) {
                float wv = wf2[o];
                twf2[o] = (fabsf(wv) > delta) ? copysignf(alpha, wv) : 0.f;
            }
            break;
    }
}

// ---------------- stage B: delta (redundant) + masked partials -------------
__global__ void tern_stageB(const float* __restrict__ wf1,
                            const float* __restrict__ part_sum,
                            float* __restrict__ part_sa,
                            float* __restrict__ part_cnt) {
    __shared__ float red[256];
    const int t = threadIdx.x;
    const int bid = blockIdx.x;

    float v = (t < WF1_SLICES) ? part_sum[t] : 0.f;
    const float delta = 0.7f * block_reduce_256(v, red, t) / (float)WF1_N;

    const float4* src = reinterpret_cast<const float4*>(wf1 + (size_t)bid * WF1_SLICE);
    float sa = 0.f, cnt = 0.f;
#pragma unroll
    for (int j = 0; j < 4; ++j) {
        const float4 w4 = src[t + j * 256];
        float a;
        a = fabsf(w4.x); if (a > delta) { sa += a; cnt += 1.f; }
        a = fabsf(w4.y); if (a > delta) { sa += a; cnt += 1.f; }
        a = fabsf(w4.z); if (a > delta) { sa += a; cnt += 1.f; }
        a = fabsf(w4.w); if (a > delta) { sa += a; cnt += 1.f; }
    }
    const float tot_sa = block_reduce_256(sa, red, t);
    const float tot_cnt = block_reduce_256(cnt, red, t);
    if (t == 0) { part_sa[bid] = tot_sa; part_cnt[bid] = tot_cnt; }
}

// ---------------- stage C: alpha (redundant) + f16 ternary write -----------
// twf1 keeps wf1's native [n=128][k=2048] orientation (no transpose).
__global__ void tern_stageC(const float* __restrict__ wf1,
                            const float* __restrict__ part_sum,
                            const float* __restrict__ part_sa,
                            const float* __restrict__ part_cnt,
                            _Float16* __restrict__ twf1) {
    __shared__ float red[256];
    const int t = threadIdx.x;

    float v = (t < WF1_SLICES) ? part_sum[t] : 0.f;
    const float delta = 0.7f * block_reduce_256(v, red, t) / (float)WF1_N;
    v = (t < WF1_SLICES) ? part_sa[t] : 0.f;
    const float tot_sa = block_reduce_256(v, red, t);
    v = (t < WF1_SLICES) ? part_cnt[t] : 0.f;
    const float tot_cnt = block_reduce_256(v, red, t);
    const float alpha = tot_sa / fmaxf(tot_cnt, 1.0f);

    const int tid = blockIdx.x * 256 + t;  // 65536 threads x 4 elems
    const float4 w4 = reinterpret_cast<const float4*>(wf1)[tid];
    half4 hv;
    hv[0] = (_Float16)((fabsf(w4.x) > delta) ? copysignf(alpha, w4.x) : 0.f);
    hv[1] = (_Float16)((fabsf(w4.y) > delta) ? copysignf(alpha, w4.y) : 0.f);
    hv[2] = (_Float16)((fabsf(w4.z) > delta) ? copysignf(alpha, w4.z) : 0.f);
    hv[3] = (_Float16)((fabsf(w4.w) > delta) ? copysignf(alpha, w4.w) : 0.f);
    reinterpret_cast<half4*>(twf1)[tid] = hv;
}

// ---------------- fused conv1(MFMA)+pool + conv2(MFMA)+pool ----------------
#define H1P 20     // f16 per h1 pixel slot (16 ci + 4 pad)
#define PSZ 3472   // 3*34*34 + 4 pad f16

__global__ __launch_bounds__(256, 4)
void conv12_kernel(const float* __restrict__ x,      // [B,3,32,32]
                   const float* __restrict__ b1,     // [16]
                   const float* __restrict__ b2,     // [32]
                   const _Float16* __restrict__ tw1f,// [3][64][4] f16 B-frags
                   const _Float16* __restrict__ tw2f,// [9][2][64][4] f16 B-frags
                   _Float16* __restrict__ h2p) {     // [B,2048] f16
    __shared__ __align__(16) _Float16 PA[PSZ];          // planar f16 [3][34][34]
    __shared__ __align__(16) _Float16 PB[PSZ];          // PB[i] = PA[i+1]
    __shared__ __align__(16) _Float16 h1s[18 * 18 * H1P];
    __shared__ __align__(16) _Float16 h2s[2048];        // co*64 + py*8 + px
    __shared__ float b1s[16], b2s[32];

    const int t = threadIdx.x;
    const int b = blockIdx.x;
    const int wid = t >> 6, l = t & 63;

    // phase 0: zero LDS (halos / garbage-tap safety) + biases
    {
        unsigned* pa = reinterpret_cast<unsigned*>(PA);
        unsigned* pb = reinterpret_cast<unsigned*>(PB);
        for (int i = t; i < PSZ / 2; i += 256) { pa[i] = 0u; pb[i] = 0u; }
        unsigned* q = reinterpret_cast<unsigned*>(h1s);
        for (int i = t; i < 18 * 18 * H1P / 2; i += 256) q[i] = 0u;
        if (t < 16) b1s[t] = b1[t];
        if (t < 32) b2s[t] = b2[t];
    }
    __syncthreads();

    // phase 1: stage x -> planar f16 (PA) + shifted copy (PB)
    {
        const float* xb = x + (size_t)b * 3072;
        for (int i = t; i < 3072; i += 256) {
            const int c = i >> 10, rem = i & 1023;
            const int iy = rem >> 5, ix = rem & 31;
            const _Float16 h = (_Float16)xb[i];
            const int idx = (c * 34 + iy + 1) * 34 + ix + 1;
            PA[idx] = h;
            PB[idx - 1] = h;
        }
    }
    __syncthreads();

    // phase 2: conv1 via 3x chained 16x16x16 MFMA (K-rows (c,ky) x 4 taps)
    {
        const int r15 = l & 15, g = l >> 4;
        const int p = r15 & 1;
        // lane-const u32 base indices for the 3 K-row groups
        int laneIdx[3];
#pragma unroll
        for (int m = 0; m < 3; ++m) {
            int rho = m * 4 + g;
            if (rho > 8) rho = 0;  // dead rows: B is zero there, any finite read ok
            const int c = rho / 3, ky = rho % 3;
            laneIdx[m] = ((c * 34 + ky) * 34 + r15 - p) >> 1;
        }
        const unsigned* basep = p ? reinterpret_cast<const unsigned*>(PB)
                                  : reinterpret_cast<const unsigned*>(PA);
        // B-frags (global, coalesced)
        half4 bfr1[3];
#pragma unroll
        for (int m = 0; m < 3; ++m)
            bfr1[m] = *reinterpret_cast<const half4*>(tw1f + (size_t)(m * 64 + l) * 4);
        const float bia = b1s[r15];

#pragma unroll 1
        for (int i = 0; i < 8; ++i) {
            const int P = wid * 8 + i;
            const int py = P >> 1, xh = P & 1;
            const int x0 = xh * 16;
            f32x4 accA = {0.f, 0.f, 0.f, 0.f};
            f32x4 accB = {0.f, 0.f, 0.f, 0.f};
#pragma unroll
            for (int h2 = 0; h2 < 2; ++h2) {
                const int y = 2 * py + h2;
                const int uoff = (y * 34 + x0) >> 1;
                f32x4 acc = {0.f, 0.f, 0.f, 0.f};
#pragma unroll
                for (int m = 0; m < 3; ++m) {
                    const unsigned* q = basep + laneIdx[m] + uoff;
                    u32x2 d;
                    d.x = q[0];
                    d.y = q[1];
                    const half4 a = __builtin_bit_cast(half4, d);
                    acc = __builtin_amdgcn_mfma_f32_16x16x16f16(a, bfr1[m], acc, 0, 0, 0);
                }
                if (h2 == 0) accA = acc; else accB = acc;
            }
            // 2x2 maxpool on regs (x = g*4 + reg), then bias+relu
            float e0 = fmaxf(fmaxf(accA[0], accA[1]), fmaxf(accB[0], accB[1]));
            float e1 = fmaxf(fmaxf(accA[2], accA[3]), fmaxf(accB[2], accB[3]));
            e0 = fmaxf(e0 + bia, 0.f);
            e1 = fmaxf(e1 + bia, 0.f);
            const int px0 = xh * 8 + g * 2;
            const int pix = (py + 1) * 18 + (px0 + 1);
            h1s[pix * H1P + r15]       = (_Float16)e0;
            h1s[(pix + 1) * H1P + r15] = (_Float16)e1;
        }
    }

    // conv2 B-frags (global, per-lane 8B, coalesced)
    half4 bfr[9][2];
#pragma unroll
    for (int s = 0; s < 9; ++s)
#pragma unroll
        for (int nt = 0; nt < 2; ++nt)
            bfr[s][nt] = *reinterpret_cast<const half4*>(
                tw2f + (size_t)((s * 2 + nt) * 64 + l) * 4);
    __syncthreads();

    // phase 3: conv2 (9-shift MFMA) + bias + relu + pool
    {
        const int xq = l & 15, g = l >> 4;
        float sav[2][2];
#pragma unroll
        for (int yy = 0; yy < 4; ++yy) {
            const int y = wid * 4 + yy;
            f32x4 acc0 = {0.f, 0.f, 0.f, 0.f};
            f32x4 acc1 = {0.f, 0.f, 0.f, 0.f};
#pragma unroll
            for (int s = 0; s < 9; ++s) {
                const int dy = s / 3, dx = s % 3;
                const half4 a = *reinterpret_cast<const half4*>(
                    &h1s[((y + dy) * 18 + (xq + dx)) * H1P + g * 4]);
                acc0 = __builtin_amdgcn_mfma_f32_16x16x16f16(a, bfr[s][0], acc0, 0, 0, 0);
                acc1 = __builtin_amdgcn_mfma_f32_16x16x16f16(a, bfr[s][1], acc1, 0, 0, 0);
            }
            // x-pool: lane regs are pixels x = g*4 + r
            const float p00 = fmaxf(acc0[0], acc0[1]);
            const float p01 = fmaxf(acc0[2], acc0[3]);
            const float p10 = fmaxf(acc1[0], acc1[1]);
            const float p11 = fmaxf(acc1[2], acc1[3]);
            if ((yy & 1) == 0) {
                sav[0][0] = p00; sav[0][1] = p01;
                sav[1][0] = p10; sav[1][1] = p11;
            } else {
                const int py = (wid * 4 + yy) >> 1;
                const float v00 = fmaxf(fmaxf(sav[0][0], p00) + b2s[xq], 0.f);
                const float v01 = fmaxf(fmaxf(sav[0][1], p01) + b2s[xq], 0.f);
                const float v10 = fmaxf(fmaxf(sav[1][0], p10) + b2s[xq + 16], 0.f);
                const float v11 = fmaxf(fmaxf(sav[1][1], p11) + b2s[xq + 16], 0.f);
                unsigned* h2u = reinterpret_cast<unsigned*>(h2s);
                h2u[xq * 32 + py * 4 + g]        = pk16(v00, v01);
                h2u[(xq + 16) * 32 + py * 4 + g] = pk16(v10, v11);
            }
        }
    }
    __syncthreads();

    // phase 4: h2s -> global (coalesced 16B/thread)
    {
        const float4 v = reinterpret_cast<const float4*>(h2s)[t];
        reinterpret_cast<float4*>(h2p + (size_t)b * 2048)[t] = v;
    }
}

// ---------------- fc1 (MFMA f16) + relu + fc2 (fp32) fused -----------------
__global__ __launch_bounds__(256, 2)
void fc_kernel(const _Float16* __restrict__ h2p,   // [B,2048]
               const _Float16* __restrict__ twf1,  // [128 n][2048 k]
               const float* __restrict__ bf1,      // [128]
               const float* __restrict__ twf2,     // [10][128]
               const float* __restrict__ bf2,      // [10]
               float* __restrict__ out) {          // [B,10]
    __shared__ _Float16 Al[4 * 64 * 8];   // 4096 B, fragment-ordered
    __shared__ _Float16 Bl[8 * 64 * 8];   // 8192 B, fragment-ordered
    __shared__ float Hs[64][132];         // 33792 B

    const int t = threadIdx.x;
    const int m0 = blockIdx.x * 64;
    const int wid = t >> 6, l = t & 63;
    const int lx = l & 15, g = l >> 4;

    f32x4 acc[8];
#pragma unroll
    for (int nt = 0; nt < 8; ++nt) acc[nt] = (f32x4){0.f, 0.f, 0.f, 0.f};

    for (int k0 = 0; k0 < 2048; k0 += 32) {
        // stage A fragments: entry t = (wave w, lane l)
        {
            const _Float16* src = h2p + (size_t)(m0 + wid * 16 + lx) * 2048 + k0 + g * 8;
            reinterpret_cast<float4*>(Al)[t] = *reinterpret_cast<const float4*>(src);
        }
        // stage B fragments: 512 entries, 2 per thread
        {
#pragma unroll
            for (int c = 0; c < 2; ++c) {
                const int e = t + c * 256;
                const int nt = e >> 6, el = e & 63;
                const _Float16* src = twf1 + (size_t)(nt * 16 + (el & 15)) * 2048 + k0 + (el >> 4) * 8;
                reinterpret_cast<float4*>(Bl)[e] = *reinterpret_cast<const float4*>(src);
            }
        }
        __syncthreads();
        const half8 a = reinterpret_cast<const half8*>(Al)[wid * 64 + l];
#pragma unroll
        for (int nt = 0; nt < 8; ++nt) {
            const half8 bb = reinterpret_cast<const half8*>(Bl)[nt * 64 + l];
            acc[nt] = __builtin_amdgcn_mfma_f32_16x16x32_f16(a, bb, acc[nt], 0, 0, 0);
        }
        __syncthreads();
    }

    // bias + relu -> Hs  (D: row = g*4+r within tile, col = lx + nt*16)
#pragma unroll
    for (int nt = 0; nt < 8; ++nt) {
        const int n = nt * 16 + lx;
        const float bias = bf1[n];
#pragma unroll
        for (int r = 0; r < 4; ++r)
            Hs[wid * 16 + g * 4 + r][n] = fmaxf(acc[nt][r] + bias, 0.f);
    }
    __syncthreads();

    // fc2: 640 outputs (64 rows x 10)
    for (int o = t; o < 640; o += 256) {
        const int m = o / 10, n = o % 10;
        float a = bf2[n];
#pragma unroll 8
        for (int k = 0; k < 128; ++k) a += Hs[m][k] * twf2[n * 128 + k];
        out[(size_t)(m0 + m) * 10 + n] = a;
    }
}

// ---------------------------------------------------------------------------
extern "C" void kernel_launch(void* const* d_in, const int* in_sizes, int n_in,
                              void* d_out, int out_size, void* d_ws, size_t ws_size,
                              hipStream_t stream) {
    const float* x   = (const float*)d_in[0];
    const float* w1  = (const float*)d_in[1];
    const float* b1  = (const float*)d_in[2];
    const float* w2  = (const float*)d_in[3];
    const float* b2  = (const float*)d_in[4];
    const float* wf1 = (const float*)d_in[5];
    const float* bf1 = (const float*)d_in[6];
    const float* wf2 = (const float*)d_in[7];
    const float* bf2 = (const float*)d_in[8];
    float* out = (float*)d_out;
    const int B = in_sizes[0] / (3 * 32 * 32);  // 4096

    char* ws = (char*)d_ws;
    _Float16*  tw1f  = (_Float16*)(ws + 0);
    _Float16*  tw2f  = (_Float16*)(ws + 1536);
    _Float16*  twf1  = (_Float16*)(ws + 10752);
    float*     twf2  = (float*)(ws + 535040);
    _Float16*  h2p   = (_Float16*)(ws + 540160);
    float*     part_sum = (float*)(ws + 17317376);
    float*     part_sa  = part_sum + 64;
    float*     part_cnt = part_sa + 64;

    tern_stageA<<<WF1_SLICES + 3, 256, 0, stream>>>(w1, w2, wf1, wf2,
                                                    tw1f, tw2f, twf2, part_sum);
    tern_stageB<<<WF1_SLICES, 256, 0, stream>>>(wf1, part_sum, part_sa, part_cnt);
    tern_stageC<<<256, 256, 0, stream>>>(wf1, part_sum, part_sa, part_cnt, twf1);
    conv12_kernel<<<B, 256, 0, stream>>>(x, b1, b2, tw1f, tw2f, h2p);
    fc_kernel<<<B / 64, 256, 0, stream>>>(h2p, twf1, bf1, twf2, bf2, out);
}

// Round 5
// 84.182 us; speedup vs baseline: 8.7269x; 1.3947x over previous
//
#include <hip/hip_runtime.h>
#include <math.h>

// ---------------------------------------------------------------------------
// SimpleTernaryNet forward, MFMA-f16 for conv1 + conv2 + fc1.
//   tern(w) -> conv3x3(3->16)+b+relu -> maxpool2      (f16 MFMA, 9-row K=27)
//           -> conv3x3(16->32)+b+relu -> maxpool2     (f16 MFMA, 9-shift)
//           -> fc(2048->128)+b+relu                   (f16 MFMA, K-split 16 waves)
//           -> fc(128->10)+b                          (fp32 VALU)
//
// ws layout (bytes):
//   [0)         tw1f   f16 [3][64][4] conv1 B-frags   1536 B
//   [1536)      tw2f   f16 [9][2][64][4] conv2 B-frags 9216 B
//   [10752)     twf1   f16 [128 n][2048 k]            524288 B
//   [535040)    twf2   f32 [10][128]                  5120 B
//   [540160)    h2p    f16 [4096][2048]               16777216 B
//   [17317376)  partials f32 sum[64], sa[64], cnt[64]
// ---------------------------------------------------------------------------

typedef _Float16 half2v __attribute__((ext_vector_type(2)));
typedef _Float16 half4  __attribute__((ext_vector_type(4)));
typedef _Float16 half8  __attribute__((ext_vector_type(8)));
typedef float    f32x4  __attribute__((ext_vector_type(4)));
typedef unsigned u32x2  __attribute__((ext_vector_type(2)));

#define WF1_N 262144
#define WF1_SLICES 64
#define WF1_SLICE 4096

__device__ __forceinline__ float block_reduce_256(float v, float* red, int t) {
    red[t] = v; __syncthreads();
    for (int o = 128; o > 0; o >>= 1) {
        if (t < o) red[t] += red[t + o];
        __syncthreads();
    }
    float r = red[0]; __syncthreads();
    return r;
}

__device__ __forceinline__ unsigned pk16(float a, float b) {
    half2v h;
    h[0] = (_Float16)a;
    h[1] = (_Float16)b;
    return __builtin_bit_cast(unsigned, h);
}

// ---------------- stage A: wf1 partial |sum| + small tensors complete ------
__global__ void tern_stageA(const float* __restrict__ w1,
                            const float* __restrict__ w2,
                            const float* __restrict__ wf1,
                            const float* __restrict__ wf2,
                            _Float16* __restrict__ tw1f,
                            _Float16* __restrict__ tw2f,
                            float* __restrict__ twf2,
                            float* __restrict__ part_sum) {
    __shared__ float red[256];
    const int t = threadIdx.x;
    const int bid = blockIdx.x;

    if (bid < WF1_SLICES) {
        const float4* src = reinterpret_cast<const float4*>(wf1 + (size_t)bid * WF1_SLICE);
        float s = 0.f;
#pragma unroll
        for (int j = 0; j < 4; ++j) {
            const float4 v = src[t + j * 256];
            s += fabsf(v.x) + fabsf(v.y) + fabsf(v.z) + fabsf(v.w);
        }
        const float tot = block_reduce_256(s, red, t);
        if (t == 0) part_sum[bid] = tot;
        return;
    }

    const float* w;
    int n;
    const int which = bid - WF1_SLICES;  // 0:w1 1:w2 2:wf2
    switch (which) {
        case 0: w = w1;  n = 432;  break;
        case 1: w = w2;  n = 4608; break;
        default: w = wf2; n = 1280; break;
    }
    float s = 0.f;
    for (int i = t; i < n; i += 256) s += fabsf(w[i]);
    const float delta = 0.7f * block_reduce_256(s, red, t) / (float)n;
    float sa = 0.f, cnt = 0.f;
    for (int i = t; i < n; i += 256) {
        float a = fabsf(w[i]);
        if (a > delta) { sa += a; cnt += 1.f; }
    }
    const float tot_sa = block_reduce_256(sa, red, t);
    const float tot_cnt = block_reduce_256(cnt, red, t);
    const float alpha = tot_sa / fmaxf(tot_cnt, 1.0f);

    switch (which) {
        case 0:
            // conv1 B-frags: 3 MFMAs (K-rows rho=m*4+g, rho=(c,ky)), taps j=0..2.
            // entry o = (m*64 + l)*4 + j ; co = l&15 ; rho = m*4 + (l>>4)
            for (int o = t; o < 768; o += 256) {
                int j = o & 3;
                int l = (o >> 2) & 63;
                int m = o >> 8;
                int rho = m * 4 + (l >> 4);
                int co = l & 15;
                float v = 0.f;
                if (rho < 9 && j < 3) {
                    float wv = w1[co * 27 + (rho / 3) * 9 + (rho % 3) * 3 + j];
                    v = (fabsf(wv) > delta) ? copysignf(alpha, wv) : 0.f;
                }
                tw1f[o] = (_Float16)v;
            }
            break;
        case 1:
            // conv2 B-frags for 16x16x16 f16 MFMA:
            // o = ((s*2+nt)*64 + lane)*4 + j ; ci=(lane>>4)*4+j ; co=(lane&15)+nt*16
            for (int o = t; o < 4608; o += 256) {
                int j  = o & 3;
                int ll = (o >> 2) & 63;
                int nt = (o >> 8) & 1;
                int s9 = o >> 9;
                int ci = (ll >> 4) * 4 + j;
                int co = (ll & 15) + nt * 16;
                float wv = w2[(co * 16 + ci) * 9 + s9];
                float v = (fabsf(wv) > delta) ? copysignf(alpha, wv) : 0.f;
                tw2f[o] = (_Float16)v;
            }
            break;
        default:
            for (int o = t; o < 1280; o += 256) {
                float wv = wf2[o];
                twf2[o] = (fabsf(wv) > delta) ? copysignf(alpha, wv) : 0.f;
            }
            break;
    }
}

// ---------------- stage B: delta (redundant) + masked partials -------------
__global__ void tern_stageB(const float* __restrict__ wf1,
                            const float* __restrict__ part_sum,
                            float* __restrict__ part_sa,
                            float* __restrict__ part_cnt) {
    __shared__ float red[256];
    const int t = threadIdx.x;
    const int bid = blockIdx.x;

    float v = (t < WF1_SLICES) ? part_sum[t] : 0.f;
    const float delta = 0.7f * block_reduce_256(v, red, t) / (float)WF1_N;

    const float4* src = reinterpret_cast<const float4*>(wf1 + (size_t)bid * WF1_SLICE);
    float sa = 0.f, cnt = 0.f;
#pragma unroll
    for (int j = 0; j < 4; ++j) {
        const float4 w4 = src[t + j * 256];
        float a;
        a = fabsf(w4.x); if (a > delta) { sa += a; cnt += 1.f; }
        a = fabsf(w4.y); if (a > delta) { sa += a; cnt += 1.f; }
        a = fabsf(w4.z); if (a > delta) { sa += a; cnt += 1.f; }
        a = fabsf(w4.w); if (a > delta) { sa += a; cnt += 1.f; }
    }
    const float tot_sa = block_reduce_256(sa, red, t);
    const float tot_cnt = block_reduce_256(cnt, red, t);
    if (t == 0) { part_sa[bid] = tot_sa; part_cnt[bid] = tot_cnt; }
}

// ---------------- stage C: alpha (redundant) + f16 ternary write -----------
// twf1 keeps wf1's native [n=128][k=2048] orientation (no transpose).
__global__ void tern_stageC(const float* __restrict__ wf1,
                            const float* __restrict__ part_sum,
                            const float* __restrict__ part_sa,
                            const float* __restrict__ part_cnt,
                            _Float16* __restrict__ twf1) {
    __shared__ float red[256];
    const int t = threadIdx.x;

    float v = (t < WF1_SLICES) ? part_sum[t] : 0.f;
    const float delta = 0.7f * block_reduce_256(v, red, t) / (float)WF1_N;
    v = (t < WF1_SLICES) ? part_sa[t] : 0.f;
    const float tot_sa = block_reduce_256(v, red, t);
    v = (t < WF1_SLICES) ? part_cnt[t] : 0.f;
    const float tot_cnt = block_reduce_256(v, red, t);
    const float alpha = tot_sa / fmaxf(tot_cnt, 1.0f);

    const int tid = blockIdx.x * 256 + t;  // 65536 threads x 4 elems
    const float4 w4 = reinterpret_cast<const float4*>(wf1)[tid];
    half4 hv;
    hv[0] = (_Float16)((fabsf(w4.x) > delta) ? copysignf(alpha, w4.x) : 0.f);
    hv[1] = (_Float16)((fabsf(w4.y) > delta) ? copysignf(alpha, w4.y) : 0.f);
    hv[2] = (_Float16)((fabsf(w4.z) > delta) ? copysignf(alpha, w4.z) : 0.f);
    hv[3] = (_Float16)((fabsf(w4.w) > delta) ? copysignf(alpha, w4.w) : 0.f);
    reinterpret_cast<half4*>(twf1)[tid] = hv;
}

// ---------------- fused conv1(MFMA)+pool + conv2(MFMA)+pool ----------------
#define H1P 20     // f16 per h1 pixel slot (16 ci + 4 pad)
#define PSZ 3472   // 3*34*34 + 4 pad f16

__global__ __launch_bounds__(256, 4)
void conv12_kernel(const float* __restrict__ x,      // [B,3,32,32]
                   const float* __restrict__ b1,     // [16]
                   const float* __restrict__ b2,     // [32]
                   const _Float16* __restrict__ tw1f,// [3][64][4] f16 B-frags
                   const _Float16* __restrict__ tw2f,// [9][2][64][4] f16 B-frags
                   _Float16* __restrict__ h2p) {     // [B,2048] f16
    __shared__ __align__(16) _Float16 PA[PSZ];          // planar f16 [3][34][34]
    __shared__ __align__(16) _Float16 PB[PSZ];          // PB[i] = PA[i+1]
    __shared__ __align__(16) _Float16 h1s[18 * 18 * H1P];
    __shared__ __align__(16) _Float16 h2s[2048];        // co*64 + py*8 + px
    __shared__ float b1s[16], b2s[32];

    const int t = threadIdx.x;
    const int b = blockIdx.x;
    const int wid = t >> 6, l = t & 63;

    // phase 0: zero LDS (halos / garbage-tap safety) + biases
    {
        unsigned* pa = reinterpret_cast<unsigned*>(PA);
        unsigned* pb = reinterpret_cast<unsigned*>(PB);
        for (int i = t; i < PSZ / 2; i += 256) { pa[i] = 0u; pb[i] = 0u; }
        unsigned* q = reinterpret_cast<unsigned*>(h1s);
        for (int i = t; i < 18 * 18 * H1P / 2; i += 256) q[i] = 0u;
        if (t < 16) b1s[t] = b1[t];
        if (t < 32) b2s[t] = b2[t];
    }
    __syncthreads();

    // phase 1: stage x -> planar f16 (PA) + shifted copy (PB)
    {
        const float* xb = x + (size_t)b * 3072;
        for (int i = t; i < 3072; i += 256) {
            const int c = i >> 10, rem = i & 1023;
            const int iy = rem >> 5, ix = rem & 31;
            const _Float16 h = (_Float16)xb[i];
            const int idx = (c * 34 + iy + 1) * 34 + ix + 1;
            PA[idx] = h;
            PB[idx - 1] = h;
        }
    }
    __syncthreads();

    // phase 2: conv1 via 3x chained 16x16x16 MFMA (K-rows (c,ky) x 4 taps)
    {
        const int r15 = l & 15, g = l >> 4;
        const int p = r15 & 1;
        // lane-const u32 base indices for the 3 K-row groups
        int laneIdx[3];
#pragma unroll
        for (int m = 0; m < 3; ++m) {
            int rho = m * 4 + g;
            if (rho > 8) rho = 0;  // dead rows: B is zero there, any finite read ok
            const int c = rho / 3, ky = rho % 3;
            laneIdx[m] = ((c * 34 + ky) * 34 + r15 - p) >> 1;
        }
        const unsigned* basep = p ? reinterpret_cast<const unsigned*>(PB)
                                  : reinterpret_cast<const unsigned*>(PA);
        // B-frags (global, coalesced)
        half4 bfr1[3];
#pragma unroll
        for (int m = 0; m < 3; ++m)
            bfr1[m] = *reinterpret_cast<const half4*>(tw1f + (size_t)(m * 64 + l) * 4);
        const float bia = b1s[r15];

#pragma unroll 1
        for (int i = 0; i < 8; ++i) {
            const int P = wid * 8 + i;
            const int py = P >> 1, xh = P & 1;
            const int x0 = xh * 16;
            f32x4 accA = {0.f, 0.f, 0.f, 0.f};
            f32x4 accB = {0.f, 0.f, 0.f, 0.f};
#pragma unroll
            for (int h2 = 0; h2 < 2; ++h2) {
                const int y = 2 * py + h2;
                const int uoff = (y * 34 + x0) >> 1;
                f32x4 acc = {0.f, 0.f, 0.f, 0.f};
#pragma unroll
                for (int m = 0; m < 3; ++m) {
                    const unsigned* q = basep + laneIdx[m] + uoff;
                    u32x2 d;
                    d.x = q[0];
                    d.y = q[1];
                    const half4 a = __builtin_bit_cast(half4, d);
                    acc = __builtin_amdgcn_mfma_f32_16x16x16f16(a, bfr1[m], acc, 0, 0, 0);
                }
                if (h2 == 0) accA = acc; else accB = acc;
            }
            // 2x2 maxpool on regs (x = g*4 + reg), then bias+relu
            float e0 = fmaxf(fmaxf(accA[0], accA[1]), fmaxf(accB[0], accB[1]));
            float e1 = fmaxf(fmaxf(accA[2], accA[3]), fmaxf(accB[2], accB[3]));
            e0 = fmaxf(e0 + bia, 0.f);
            e1 = fmaxf(e1 + bia, 0.f);
            const int px0 = xh * 8 + g * 2;
            const int pix = (py + 1) * 18 + (px0 + 1);
            h1s[pix * H1P + r15]       = (_Float16)e0;
            h1s[(pix + 1) * H1P + r15] = (_Float16)e1;
        }
    }

    // conv2 B-frags (global, per-lane 8B, coalesced)
    half4 bfr[9][2];
#pragma unroll
    for (int s = 0; s < 9; ++s)
#pragma unroll
        for (int nt = 0; nt < 2; ++nt)
            bfr[s][nt] = *reinterpret_cast<const half4*>(
                tw2f + (size_t)((s * 2 + nt) * 64 + l) * 4);
    __syncthreads();

    // phase 3: conv2 (9-shift MFMA) + bias + relu + pool
    {
        const int xq = l & 15, g = l >> 4;
        float sav[2][2];
#pragma unroll
        for (int yy = 0; yy < 4; ++yy) {
            const int y = wid * 4 + yy;
            f32x4 acc0 = {0.f, 0.f, 0.f, 0.f};
            f32x4 acc1 = {0.f, 0.f, 0.f, 0.f};
#pragma unroll
            for (int s = 0; s < 9; ++s) {
                const int dy = s / 3, dx = s % 3;
                const half4 a = *reinterpret_cast<const half4*>(
                    &h1s[((y + dy) * 18 + (xq + dx)) * H1P + g * 4]);
                acc0 = __builtin_amdgcn_mfma_f32_16x16x16f16(a, bfr[s][0], acc0, 0, 0, 0);
                acc1 = __builtin_amdgcn_mfma_f32_16x16x16f16(a, bfr[s][1], acc1, 0, 0, 0);
            }
            // x-pool: lane regs are pixels x = g*4 + r
            const float p00 = fmaxf(acc0[0], acc0[1]);
            const float p01 = fmaxf(acc0[2], acc0[3]);
            const float p10 = fmaxf(acc1[0], acc1[1]);
            const float p11 = fmaxf(acc1[2], acc1[3]);
            if ((yy & 1) == 0) {
                sav[0][0] = p00; sav[0][1] = p01;
                sav[1][0] = p10; sav[1][1] = p11;
            } else {
                const int py = (wid * 4 + yy) >> 1;
                const float v00 = fmaxf(fmaxf(sav[0][0], p00) + b2s[xq], 0.f);
                const float v01 = fmaxf(fmaxf(sav[0][1], p01) + b2s[xq], 0.f);
                const float v10 = fmaxf(fmaxf(sav[1][0], p10) + b2s[xq + 16], 0.f);
                const float v11 = fmaxf(fmaxf(sav[1][1], p11) + b2s[xq + 16], 0.f);
                unsigned* h2u = reinterpret_cast<unsigned*>(h2s);
                h2u[xq * 32 + py * 4 + g]        = pk16(v00, v01);
                h2u[(xq + 16) * 32 + py * 4 + g] = pk16(v10, v11);
            }
        }
    }
    __syncthreads();

    // phase 4: h2s -> global (coalesced 16B/thread)
    {
        const float4 v = reinterpret_cast<const float4*>(h2s)[t];
        reinterpret_cast<float4*>(h2p + (size_t)b * 2048)[t] = v;
    }
}

// ---------------- fc1 (MFMA f16, K-split over 16 waves) + fc2 fused --------
// grid = B/16 blocks x 1024 threads. Wave w owns K-chunk [w*128,(w+1)*128).
// No LDS staging in K-loop; fragments loaded straight from global.
__global__ __launch_bounds__(1024, 4)
void fc_kernel(const _Float16* __restrict__ h2p,   // [B,2048]
               const _Float16* __restrict__ twf1,  // [128 n][2048 k]
               const float* __restrict__ bf1,      // [128]
               const float* __restrict__ twf2,     // [10][128]
               const float* __restrict__ bf2,      // [10]
               float* __restrict__ out) {          // [B,10]
    __shared__ float red[8][2048];                 // 64 KB reduction buffer

    const int t = threadIdx.x;
    const int wid = t >> 6, l = t & 63;
    const int lx = l & 15, g = l >> 4;
    const int m0 = blockIdx.x * 16;

    f32x4 acc[8];
#pragma unroll
    for (int nt = 0; nt < 8; ++nt) acc[nt] = (f32x4){0.f, 0.f, 0.f, 0.f};

    const int kb = wid * 128;
#pragma unroll
    for (int it = 0; it < 4; ++it) {
        const int k0 = kb + it * 32;
        const half8 a = *reinterpret_cast<const half8*>(
            h2p + (size_t)(m0 + lx) * 2048 + k0 + g * 8);
#pragma unroll
        for (int nt = 0; nt < 8; ++nt) {
            const half8 bb = *reinterpret_cast<const half8*>(
                twf1 + (size_t)(nt * 16 + lx) * 2048 + k0 + g * 8);
            acc[nt] = __builtin_amdgcn_mfma_f32_16x16x32_f16(a, bb, acc[nt], 0, 0, 0);
        }
    }

    // tree-reduce 16 wave partials -> wave 0
    for (int h = 8; h >= 1; h >>= 1) {
        if (wid >= h && wid < 2 * h) {
            float* dst = &red[wid - h][0];
#pragma unroll
            for (int nt = 0; nt < 8; ++nt)
                *reinterpret_cast<f32x4*>(dst + nt * 256 + l * 4) = acc[nt];
        }
        __syncthreads();
        if (wid < h) {
            const float* srcp = &red[wid][0];
#pragma unroll
            for (int nt = 0; nt < 8; ++nt) {
                const f32x4 v = *reinterpret_cast<const f32x4*>(srcp + nt * 256 + l * 4);
                acc[nt] += v;
            }
        }
        __syncthreads();
    }

    // wave 0: bias + relu -> Hs (stored in red[0..1])
    if (wid == 0) {
#pragma unroll
        for (int nt = 0; nt < 8; ++nt) {
            const int col = nt * 16 + lx;
            const float bias = bf1[col];
#pragma unroll
            for (int r = 0; r < 4; ++r)
                red[0][(g * 4 + r) * 128 + col] = fmaxf(acc[nt][r] + bias, 0.f);
        }
    }
    __syncthreads();

    // fc2: 160 outputs (16 rows x 10)
    if (t < 160) {
        const int m = t / 10, n = t % 10;
        float a = bf2[n];
#pragma unroll 8
        for (int k = 0; k < 128; ++k) a += red[0][m * 128 + k] * twf2[n * 128 + k];
        out[(size_t)(m0 + m) * 10 + n] = a;
    }
}

// ---------------------------------------------------------------------------
extern "C" void kernel_launch(void* const* d_in, const int* in_sizes, int n_in,
                              void* d_out, int out_size, void* d_ws, size_t ws_size,
                              hipStream_t stream) {
    const float* x   = (const float*)d_in[0];
    const float* w1  = (const float*)d_in[1];
    const float* b1  = (const float*)d_in[2];
    const float* w2  = (const float*)d_in[3];
    const float* b2  = (const float*)d_in[4];
    const float* wf1 = (const float*)d_in[5];
    const float* bf1 = (const float*)d_in[6];
    const float* wf2 = (const float*)d_in[7];
    const float* bf2 = (const float*)d_in[8];
    float* out = (float*)d_out;
    const int B = in_sizes[0] / (3 * 32 * 32);  // 4096

    char* ws = (char*)d_ws;
    _Float16*  tw1f  = (_Float16*)(ws + 0);
    _Float16*  tw2f  = (_Float16*)(ws + 1536);
    _Float16*  twf1  = (_Float16*)(ws + 10752);
    float*     twf2  = (float*)(ws + 535040);
    _Float16*  h2p   = (_Float16*)(ws + 540160);
    float*     part_sum = (float*)(ws + 17317376);
    float*     part_sa  = part_sum + 64;
    float*     part_cnt = part_sa + 64;

    tern_stageA<<<WF1_SLICES + 3, 256, 0, stream>>>(w1, w2, wf1, wf2,
                                                    tw1f, tw2f, twf2, part_sum);
    tern_stageB<<<WF1_SLICES, 256, 0, stream>>>(wf1, part_sum, part_sa, part_cnt);
    tern_stageC<<<256, 256, 0, stream>>>(wf1, part_sum, part_sa, part_cnt, twf1);
    conv12_kernel<<<B, 256, 0, stream>>>(x, b1, b2, tw1f, tw2f, h2p);
    fc_kernel<<<B / 16, 1024, 0, stream>>>(h2p, twf1, bf1, twf2, bf2, out);
}

// Round 6
// 76.062 us; speedup vs baseline: 9.6586x; 1.1068x over previous
//
#include <hip/hip_runtime.h>
#include <math.h>

// ---------------------------------------------------------------------------
// SimpleTernaryNet forward, MFMA-f16 for conv1 + conv2 + fc1.
//   tern(w) -> conv3x3(3->16)+b+relu -> maxpool2      (f16 MFMA, 9-row K=27)
//           -> conv3x3(16->32)+b+relu -> maxpool2     (f16 MFMA, 9-shift)
//           -> fc(2048->128)+b+relu                   (f16 MFMA, K-split 16 waves)
//           -> fc(128->10)+b                          (fp32 VALU)
//
// ws layout (bytes):
//   [0)         tw1f   f16 [3][64][4] conv1 B-frags   1536 B
//   [1536)      tw2f   f16 [9][2][64][4] conv2 B-frags 9216 B
//   [10752)     twf1   f16 [128 n][2048 k]            524288 B
//   [535040)    twf2   f32 [10][128]                  5120 B
//   [540160)    h2p    f16 [4096][2048]               16777216 B
//   [17317376)  partials f32 sum[64], sa[64], cnt[64]
// ---------------------------------------------------------------------------

typedef _Float16 half2v __attribute__((ext_vector_type(2)));
typedef _Float16 half4  __attribute__((ext_vector_type(4)));
typedef _Float16 half8  __attribute__((ext_vector_type(8)));
typedef float    f32x4  __attribute__((ext_vector_type(4)));
typedef unsigned u32x2  __attribute__((ext_vector_type(2)));

#define WF1_N 262144
#define WF1_SLICES 64
#define WF1_SLICE 4096

__device__ __forceinline__ float block_reduce_256(float v, float* red, int t) {
    red[t] = v; __syncthreads();
    for (int o = 128; o > 0; o >>= 1) {
        if (t < o) red[t] += red[t + o];
        __syncthreads();
    }
    float r = red[0]; __syncthreads();
    return r;
}

__device__ __forceinline__ unsigned pk16(float a, float b) {
    half2v h;
    h[0] = (_Float16)a;
    h[1] = (_Float16)b;
    return __builtin_bit_cast(unsigned, h);
}

// ---------------- stage A: wf1 partial |sum| + small tensors complete ------
__global__ void tern_stageA(const float* __restrict__ w1,
                            const float* __restrict__ w2,
                            const float* __restrict__ wf1,
                            const float* __restrict__ wf2,
                            _Float16* __restrict__ tw1f,
                            _Float16* __restrict__ tw2f,
                            float* __restrict__ twf2,
                            float* __restrict__ part_sum) {
    __shared__ float red[256];
    const int t = threadIdx.x;
    const int bid = blockIdx.x;

    if (bid < WF1_SLICES) {
        const float4* src = reinterpret_cast<const float4*>(wf1 + (size_t)bid * WF1_SLICE);
        float s = 0.f;
#pragma unroll
        for (int j = 0; j < 4; ++j) {
            const float4 v = src[t + j * 256];
            s += fabsf(v.x) + fabsf(v.y) + fabsf(v.z) + fabsf(v.w);
        }
        const float tot = block_reduce_256(s, red, t);
        if (t == 0) part_sum[bid] = tot;
        return;
    }

    const float* w;
    int n;
    const int which = bid - WF1_SLICES;  // 0:w1 1:w2 2:wf2
    switch (which) {
        case 0: w = w1;  n = 432;  break;
        case 1: w = w2;  n = 4608; break;
        default: w = wf2; n = 1280; break;
    }
    float s = 0.f;
    for (int i = t; i < n; i += 256) s += fabsf(w[i]);
    const float delta = 0.7f * block_reduce_256(s, red, t) / (float)n;
    float sa = 0.f, cnt = 0.f;
    for (int i = t; i < n; i += 256) {
        float a = fabsf(w[i]);
        if (a > delta) { sa += a; cnt += 1.f; }
    }
    const float tot_sa = block_reduce_256(sa, red, t);
    const float tot_cnt = block_reduce_256(cnt, red, t);
    const float alpha = tot_sa / fmaxf(tot_cnt, 1.0f);

    switch (which) {
        case 0:
            // conv1 B-frags: 3 MFMAs (K-rows rho=m*4+g, rho=(c,ky)), taps j=0..2.
            // entry o = (m*64 + l)*4 + j ; co = l&15 ; rho = m*4 + (l>>4)
            for (int o = t; o < 768; o += 256) {
                int j = o & 3;
                int l = (o >> 2) & 63;
                int m = o >> 8;
                int rho = m * 4 + (l >> 4);
                int co = l & 15;
                float v = 0.f;
                if (rho < 9 && j < 3) {
                    float wv = w1[co * 27 + (rho / 3) * 9 + (rho % 3) * 3 + j];
                    v = (fabsf(wv) > delta) ? copysignf(alpha, wv) : 0.f;
                }
                tw1f[o] = (_Float16)v;
            }
            break;
        case 1:
            // conv2 B-frags for 16x16x16 f16 MFMA:
            // o = ((s*2+nt)*64 + lane)*4 + j ; ci=(lane>>4)*4+j ; co=(lane&15)+nt*16
            for (int o = t; o < 4608; o += 256) {
                int j  = o & 3;
                int ll = (o >> 2) & 63;
                int nt = (o >> 8) & 1;
                int s9 = o >> 9;
                int ci = (ll >> 4) * 4 + j;
                int co = (ll & 15) + nt * 16;
                float wv = w2[(co * 16 + ci) * 9 + s9];
                float v = (fabsf(wv) > delta) ? copysignf(alpha, wv) : 0.f;
                tw2f[o] = (_Float16)v;
            }
            break;
        default:
            for (int o = t; o < 1280; o += 256) {
                float wv = wf2[o];
                twf2[o] = (fabsf(wv) > delta) ? copysignf(alpha, wv) : 0.f;
            }
            break;
    }
}

// ---------------- stage B: delta (redundant) + masked partials -------------
__global__ void tern_stageB(const float* __restrict__ wf1,
                            const float* __restrict__ part_sum,
                            float* __restrict__ part_sa,
                            float* __restrict__ part_cnt) {
    __shared__ float red[256];
    const int t = threadIdx.x;
    const int bid = blockIdx.x;

    float v = (t < WF1_SLICES) ? part_sum[t] : 0.f;
    const float delta = 0.7f * block_reduce_256(v, red, t) / (float)WF1_N;

    const float4* src = reinterpret_cast<const float4*>(wf1 + (size_t)bid * WF1_SLICE);
    float sa = 0.f, cnt = 0.f;
#pragma unroll
    for (int j = 0; j < 4; ++j) {
        const float4 w4 = src[t + j * 256];
        float a;
        a = fabsf(w4.x); if (a > delta) { sa += a; cnt += 1.f; }
        a = fabsf(w4.y); if (a > delta) { sa += a; cnt += 1.f; }
        a = fabsf(w4.z); if (a > delta) { sa += a; cnt += 1.f; }
        a = fabsf(w4.w); if (a > delta) { sa += a; cnt += 1.f; }
    }
    const float tot_sa = block_reduce_256(sa, red, t);
    const float tot_cnt = block_reduce_256(cnt, red, t);
    if (t == 0) { part_sa[bid] = tot_sa; part_cnt[bid] = tot_cnt; }
}

// ---------------- stage C: alpha (redundant) + f16 ternary write -----------
// twf1 keeps wf1's native [n=128][k=2048] orientation (no transpose).
__global__ void tern_stageC(const float* __restrict__ wf1,
                            const float* __restrict__ part_sum,
                            const float* __restrict__ part_sa,
                            const float* __restrict__ part_cnt,
                            _Float16* __restrict__ twf1) {
    __shared__ float red[256];
    const int t = threadIdx.x;

    float v = (t < WF1_SLICES) ? part_sum[t] : 0.f;
    const float delta = 0.7f * block_reduce_256(v, red, t) / (float)WF1_N;
    v = (t < WF1_SLICES) ? part_sa[t] : 0.f;
    const float tot_sa = block_reduce_256(v, red, t);
    v = (t < WF1_SLICES) ? part_cnt[t] : 0.f;
    const float tot_cnt = block_reduce_256(v, red, t);
    const float alpha = tot_sa / fmaxf(tot_cnt, 1.0f);

    const int tid = blockIdx.x * 256 + t;  // 65536 threads x 4 elems
    const float4 w4 = reinterpret_cast<const float4*>(wf1)[tid];
    half4 hv;
    hv[0] = (_Float16)((fabsf(w4.x) > delta) ? copysignf(alpha, w4.x) : 0.f);
    hv[1] = (_Float16)((fabsf(w4.y) > delta) ? copysignf(alpha, w4.y) : 0.f);
    hv[2] = (_Float16)((fabsf(w4.z) > delta) ? copysignf(alpha, w4.z) : 0.f);
    hv[3] = (_Float16)((fabsf(w4.w) > delta) ? copysignf(alpha, w4.w) : 0.f);
    reinterpret_cast<half4*>(twf1)[tid] = hv;
}

// ---------------- fused conv1(MFMA)+pool + conv2(MFMA)+pool ----------------
// H1P=18: pixel stride 9 dwords (odd) -> conv2 A-read bank conflicts 2-way (free).
#define H1P 18
#define PSZ 3472          // 3*34*34=3468 + 4 pad f16 (6944 B, /16 ok)
#define H1SZ (18*18*H1P)  // 5832 f16 = 11664 B (/16 ok)

__global__ __launch_bounds__(256, 4)
void conv12_kernel(const float* __restrict__ x,      // [B,3,32,32]
                   const float* __restrict__ b1,     // [16]
                   const float* __restrict__ b2,     // [32]
                   const _Float16* __restrict__ tw1f,// [3][64][4] f16 B-frags
                   const _Float16* __restrict__ tw2f,// [9][2][64][4] f16 B-frags
                   _Float16* __restrict__ h2p) {     // [B,2048] f16
    __shared__ __align__(16) _Float16 PA[PSZ];          // planar f16 [3][34][34]
    __shared__ __align__(16) _Float16 PB[PSZ];          // PB[i] = PA[i+1]
    __shared__ __align__(16) _Float16 h1s[H1SZ];        // (y*18+x)*18 + ci
    __shared__ __align__(16) _Float16 h2s[2048];        // co*64 + py*8 + px
    __shared__ float b1s[16], b2s[32];

    const int t = threadIdx.x;
    const int b = blockIdx.x;
    const int wid = t >> 6, l = t & 63;

    // issue x loads FIRST so HBM latency hides under the zero phase
    float xv[12];
    {
        const float* xb = x + (size_t)b * 3072;
#pragma unroll
        for (int j = 0; j < 12; ++j) xv[j] = xb[t + j * 256];
    }
    // conv1 B-frags (L2-resident)
    half4 bfr1[3];
#pragma unroll
    for (int m = 0; m < 3; ++m)
        bfr1[m] = *reinterpret_cast<const half4*>(tw1f + (size_t)(m * 64 + l) * 4);
    if (t < 16) b1s[t] = b1[t];
    if (t < 32) b2s[t] = b2[t];

    // zero LDS via float4 (halos / garbage-tap safety)
    {
        const float4 z = {0.f, 0.f, 0.f, 0.f};
        float4* pa4 = reinterpret_cast<float4*>(PA);
        float4* pb4 = reinterpret_cast<float4*>(PB);
        float4* h14 = reinterpret_cast<float4*>(h1s);
        for (int i = t; i < PSZ * 2 / 16; i += 256) { pa4[i] = z; pb4[i] = z; }
        for (int i = t; i < H1SZ * 2 / 16; i += 256) h14[i] = z;
    }
    __syncthreads();

    // phase 1: stage x -> planar f16 (PA) + shifted copy (PB)
    {
#pragma unroll
        for (int j = 0; j < 12; ++j) {
            const int i = t + j * 256;
            const int c = i >> 10, rem = i & 1023;
            const int iy = rem >> 5, ix = rem & 31;
            const _Float16 h = (_Float16)xv[j];
            const int idx = (c * 34 + iy + 1) * 34 + ix + 1;
            PA[idx] = h;
            PB[idx - 1] = h;
        }
    }
    __syncthreads();

    // phase 2: conv1 via 3x chained 16x16x16 MFMA (K-rows (c,ky) x 4 taps)
    {
        const int r15 = l & 15, g = l >> 4;
        const int p = r15 & 1;
        int laneIdx[3];
#pragma unroll
        for (int m = 0; m < 3; ++m) {
            int rho = m * 4 + g;
            if (rho > 8) rho = 0;  // dead rows: B is zero there, any finite read ok
            const int c = rho / 3, ky = rho % 3;
            laneIdx[m] = ((c * 34 + ky) * 34 + r15 - p) >> 1;
        }
        const unsigned* basep = p ? reinterpret_cast<const unsigned*>(PB)
                                  : reinterpret_cast<const unsigned*>(PA);
        const float bia = b1s[r15];

#pragma unroll 1
        for (int i = 0; i < 8; ++i) {
            const int P = wid * 8 + i;
            const int py = P >> 1, xh = P & 1;
            const int x0 = xh * 16;
            f32x4 accA = {0.f, 0.f, 0.f, 0.f};
            f32x4 accB = {0.f, 0.f, 0.f, 0.f};
#pragma unroll
            for (int h2 = 0; h2 < 2; ++h2) {
                const int y = 2 * py + h2;
                const int uoff = (y * 34 + x0) >> 1;
                f32x4 acc = {0.f, 0.f, 0.f, 0.f};
#pragma unroll
                for (int m = 0; m < 3; ++m) {
                    const unsigned* q = basep + laneIdx[m] + uoff;
                    u32x2 d;
                    d.x = q[0];
                    d.y = q[1];
                    const half4 a = __builtin_bit_cast(half4, d);
                    acc = __builtin_amdgcn_mfma_f32_16x16x16f16(a, bfr1[m], acc, 0, 0, 0);
                }
                if (h2 == 0) accA = acc; else accB = acc;
            }
            // 2x2 maxpool on regs (x = g*4 + reg), then bias+relu
            float e0 = fmaxf(fmaxf(accA[0], accA[1]), fmaxf(accB[0], accB[1]));
            float e1 = fmaxf(fmaxf(accA[2], accA[3]), fmaxf(accB[2], accB[3]));
            e0 = fmaxf(e0 + bia, 0.f);
            e1 = fmaxf(e1 + bia, 0.f);
            const int px0 = xh * 8 + g * 2;
            const int pix = (py + 1) * 18 + (px0 + 1);
            h1s[pix * H1P + r15]       = (_Float16)e0;
            h1s[(pix + 1) * H1P + r15] = (_Float16)e1;
        }
    }

    // conv2 B-frags (global, per-lane 8B, coalesced, L2-resident)
    half4 bfr[9][2];
#pragma unroll
    for (int s = 0; s < 9; ++s)
#pragma unroll
        for (int nt = 0; nt < 2; ++nt)
            bfr[s][nt] = *reinterpret_cast<const half4*>(
                tw2f + (size_t)((s * 2 + nt) * 64 + l) * 4);
    __syncthreads();

    // phase 3: conv2 (9-shift MFMA) + bias + relu + pool
    {
        const int xq = l & 15, g = l >> 4;
        const unsigned* h1u = reinterpret_cast<const unsigned*>(h1s);
        float sav[2][2];
#pragma unroll
        for (int yy = 0; yy < 4; ++yy) {
            const int y = wid * 4 + yy;
            // per-lane base; all 9 taps are constant dword offsets from here
            const unsigned* qb = h1u + (y * 18 + xq) * 9 + g * 2;
            f32x4 acc0 = {0.f, 0.f, 0.f, 0.f};
            f32x4 acc1 = {0.f, 0.f, 0.f, 0.f};
#pragma unroll
            for (int s = 0; s < 9; ++s) {
                const int dy = s / 3, dx = s % 3;
                const int off = (dy * 18 + dx) * 9;
                u32x2 d;
                d.x = qb[off];
                d.y = qb[off + 1];
                const half4 a = __builtin_bit_cast(half4, d);
                acc0 = __builtin_amdgcn_mfma_f32_16x16x16f16(a, bfr[s][0], acc0, 0, 0, 0);
                acc1 = __builtin_amdgcn_mfma_f32_16x16x16f16(a, bfr[s][1], acc1, 0, 0, 0);
            }
            // x-pool: lane regs are pixels x = g*4 + r
            const float p00 = fmaxf(acc0[0], acc0[1]);
            const float p01 = fmaxf(acc0[2], acc0[3]);
            const float p10 = fmaxf(acc1[0], acc1[1]);
            const float p11 = fmaxf(acc1[2], acc1[3]);
            if ((yy & 1) == 0) {
                sav[0][0] = p00; sav[0][1] = p01;
                sav[1][0] = p10; sav[1][1] = p11;
            } else {
                const int py = (wid * 4 + yy) >> 1;
                const float v00 = fmaxf(fmaxf(sav[0][0], p00) + b2s[xq], 0.f);
                const float v01 = fmaxf(fmaxf(sav[0][1], p01) + b2s[xq], 0.f);
                const float v10 = fmaxf(fmaxf(sav[1][0], p10) + b2s[xq + 16], 0.f);
                const float v11 = fmaxf(fmaxf(sav[1][1], p11) + b2s[xq + 16], 0.f);
                unsigned* h2u = reinterpret_cast<unsigned*>(h2s);
                h2u[xq * 32 + py * 4 + g]        = pk16(v00, v01);
                h2u[(xq + 16) * 32 + py * 4 + g] = pk16(v10, v11);
            }
        }
    }
    __syncthreads();

    // phase 4: h2s -> global (coalesced 16B/thread)
    {
        const float4 v = reinterpret_cast<const float4*>(h2s)[t];
        reinterpret_cast<float4*>(h2p + (size_t)b * 2048)[t] = v;
    }
}

// ---------------- fc1 (MFMA f16, K-split over 16 waves) + fc2 fused --------
// grid = B/16 blocks x 1024 threads. Wave w owns K-chunk [w*128,(w+1)*128).
// No LDS staging in K-loop; fragments loaded straight from global.
__global__ __launch_bounds__(1024, 4)
void fc_kernel(const _Float16* __restrict__ h2p,   // [B,2048]
               const _Float16* __restrict__ twf1,  // [128 n][2048 k]
               const float* __restrict__ bf1,      // [128]
               const float* __restrict__ twf2,     // [10][128]
               const float* __restrict__ bf2,      // [10]
               float* __restrict__ out) {          // [B,10]
    __shared__ float red[8][2048];                 // 64 KB reduction buffer

    const int t = threadIdx.x;
    const int wid = t >> 6, l = t & 63;
    const int lx = l & 15, g = l >> 4;
    const int m0 = blockIdx.x * 16;

    f32x4 acc[8];
#pragma unroll
    for (int nt = 0; nt < 8; ++nt) acc[nt] = (f32x4){0.f, 0.f, 0.f, 0.f};

    const int kb = wid * 128;
#pragma unroll
    for (int it = 0; it < 4; ++it) {
        const int k0 = kb + it * 32;
        const half8 a = *reinterpret_cast<const half8*>(
            h2p + (size_t)(m0 + lx) * 2048 + k0 + g * 8);
#pragma unroll
        for (int nt = 0; nt < 8; ++nt) {
            const half8 bb = *reinterpret_cast<const half8*>(
                twf1 + (size_t)(nt * 16 + lx) * 2048 + k0 + g * 8);
            acc[nt] = __builtin_amdgcn_mfma_f32_16x16x32_f16(a, bb, acc[nt], 0, 0, 0);
        }
    }

    // tree-reduce 16 wave partials -> wave 0
    for (int h = 8; h >= 1; h >>= 1) {
        if (wid >= h && wid < 2 * h) {
            float* dst = &red[wid - h][0];
#pragma unroll
            for (int nt = 0; nt < 8; ++nt)
                *reinterpret_cast<f32x4*>(dst + nt * 256 + l * 4) = acc[nt];
        }
        __syncthreads();
        if (wid < h) {
            const float* srcp = &red[wid][0];
#pragma unroll
            for (int nt = 0; nt < 8; ++nt) {
                const f32x4 v = *reinterpret_cast<const f32x4*>(srcp + nt * 256 + l * 4);
                acc[nt] += v;
            }
        }
        __syncthreads();
    }

    // wave 0: bias + relu -> Hs (stored in red[0])
    if (wid == 0) {
#pragma unroll
        for (int nt = 0; nt < 8; ++nt) {
            const int col = nt * 16 + lx;
            const float bias = bf1[col];
#pragma unroll
            for (int r = 0; r < 4; ++r)
                red[0][(g * 4 + r) * 128 + col] = fmaxf(acc[nt][r] + bias, 0.f);
        }
    }
    __syncthreads();

    // fc2: 160 outputs (16 rows x 10)
    if (t < 160) {
        const int m = t / 10, n = t % 10;
        float a = bf2[n];
#pragma unroll 8
        for (int k = 0; k < 128; ++k) a += red[0][m * 128 + k] * twf2[n * 128 + k];
        out[(size_t)(m0 + m) * 10 + n] = a;
    }
}

// ---------------------------------------------------------------------------
extern "C" void kernel_launch(void* const* d_in, const int* in_sizes, int n_in,
                              void* d_out, int out_size, void* d_ws, size_t ws_size,
                              hipStream_t stream) {
    const float* x   = (const float*)d_in[0];
    const float* w1  = (const float*)d_in[1];
    const float* b1  = (const float*)d_in[2];
    const float* w2  = (const float*)d_in[3];
    const float* b2  = (const float*)d_in[4];
    const float* wf1 = (const float*)d_in[5];
    const float* bf1 = (const float*)d_in[6];
    const float* wf2 = (const float*)d_in[7];
    const float* bf2 = (const float*)d_in[8];
    float* out = (float*)d_out;
    const int B = in_sizes[0] / (3 * 32 * 32);  // 4096

    char* ws = (char*)d_ws;
    _Float16*  tw1f  = (_Float16*)(ws + 0);
    _Float16*  tw2f  = (_Float16*)(ws + 1536);
    _Float16*  twf1  = (_Float16*)(ws + 10752);
    float*     twf2  = (float*)(ws + 535040);
    _Float16*  h2p   = (_Float16*)(ws + 540160);
    float*     part_sum = (float*)(ws + 17317376);
    float*     part_sa  = part_sum + 64;
    float*     part_cnt = part_sa + 64;

    tern_stageA<<<WF1_SLICES + 3, 256, 0, stream>>>(w1, w2, wf1, wf2,
                                                    tw1f, tw2f, twf2, part_sum);
    tern_stageB<<<WF1_SLICES, 256, 0, stream>>>(wf1, part_sum, part_sa, part_cnt);
    tern_stageC<<<256, 256, 0, stream>>>(wf1, part_sum, part_sa, part_cnt, twf1);
    conv12_kernel<<<B, 256, 0, stream>>>(x, b1, b2, tw1f, tw2f, h2p);
    fc_kernel<<<B / 16, 1024, 0, stream>>>(h2p, twf1, bf1, twf2, bf2, out);
}

// Round 8
// 75.931 us; speedup vs baseline: 9.6752x; 1.0017x over previous
//
#include <hip/hip_runtime.h>
#include <math.h>

// ---------------------------------------------------------------------------
// SimpleTernaryNet forward, MFMA-f16 for conv1 + conv2 + fc1.
//   tern(w) -> conv3x3(3->16)+b+relu -> maxpool2      (f16 MFMA, 9-row K=27)
//           -> conv3x3(16->32)+b+relu -> maxpool2     (f16 MFMA, 9-shift,
//                                                      register-blocked input)
//           -> fc(2048->128)+b+relu                   (f16 MFMA, K-split 16 waves)
//           -> fc(128->10)+b                          (fp32 VALU)
//
// Round-8 note: round-7's LDS aliasing + occupancy-6 experiment caused a
// post-timing divergence (replay nondeterminism) with zero perf gain ->
// fully reverted to the round-6 structure (separate __shared__ arrays,
// launch_bounds(256,4)). Only change vs round 6: conv2 preloads its 6x3
// pixel block into registers (36 VGPR) once, halving conv2 DS reads.
//
// ws layout (bytes):
//   [0)         tw1f   f16 [3][64][4] conv1 B-frags   1536 B
//   [1536)      tw2f   f16 [9][2][64][4] conv2 B-frags 9216 B
//   [10752)     twf1   f16 [128 n][2048 k]            524288 B
//   [535040)    twf2   f32 [10][128]                  5120 B
//   [540160)    h2p    f16 [4096][2048]               16777216 B
//   [17317376)  partials f32 sum[64], sa[64], cnt[64]
// ---------------------------------------------------------------------------

typedef _Float16 half2v __attribute__((ext_vector_type(2)));
typedef _Float16 half4  __attribute__((ext_vector_type(4)));
typedef _Float16 half8  __attribute__((ext_vector_type(8)));
typedef float    f32x4  __attribute__((ext_vector_type(4)));
typedef unsigned u32x2  __attribute__((ext_vector_type(2)));

#define WF1_N 262144
#define WF1_SLICES 64
#define WF1_SLICE 4096

__device__ __forceinline__ float block_reduce_256(float v, float* red, int t) {
    red[t] = v; __syncthreads();
    for (int o = 128; o > 0; o >>= 1) {
        if (t < o) red[t] += red[t + o];
        __syncthreads();
    }
    float r = red[0]; __syncthreads();
    return r;
}

__device__ __forceinline__ unsigned pk16(float a, float b) {
    half2v h;
    h[0] = (_Float16)a;
    h[1] = (_Float16)b;
    return __builtin_bit_cast(unsigned, h);
}

// ---------------- stage A: wf1 partial |sum| + small tensors complete ------
__global__ void tern_stageA(const float* __restrict__ w1,
                            const float* __restrict__ w2,
                            const float* __restrict__ wf1,
                            const float* __restrict__ wf2,
                            _Float16* __restrict__ tw1f,
                            _Float16* __restrict__ tw2f,
                            float* __restrict__ twf2,
                            float* __restrict__ part_sum) {
    __shared__ float red[256];
    const int t = threadIdx.x;
    const int bid = blockIdx.x;

    if (bid < WF1_SLICES) {
        const float4* src = reinterpret_cast<const float4*>(wf1 + (size_t)bid * WF1_SLICE);
        float s = 0.f;
#pragma unroll
        for (int j = 0; j < 4; ++j) {
            const float4 v = src[t + j * 256];
            s += fabsf(v.x) + fabsf(v.y) + fabsf(v.z) + fabsf(v.w);
        }
        const float tot = block_reduce_256(s, red, t);
        if (t == 0) part_sum[bid] = tot;
        return;
    }

    const float* w;
    int n;
    const int which = bid - WF1_SLICES;  // 0:w1 1:w2 2:wf2
    switch (which) {
        case 0: w = w1;  n = 432;  break;
        case 1: w = w2;  n = 4608; break;
        default: w = wf2; n = 1280; break;
    }
    float s = 0.f;
    for (int i = t; i < n; i += 256) s += fabsf(w[i]);
    const float delta = 0.7f * block_reduce_256(s, red, t) / (float)n;
    float sa = 0.f, cnt = 0.f;
    for (int i = t; i < n; i += 256) {
        float a = fabsf(w[i]);
        if (a > delta) { sa += a; cnt += 1.f; }
    }
    const float tot_sa = block_reduce_256(sa, red, t);
    const float tot_cnt = block_reduce_256(cnt, red, t);
    const float alpha = tot_sa / fmaxf(tot_cnt, 1.0f);

    switch (which) {
        case 0:
            // conv1 B-frags: 3 MFMAs (K-rows rho=m*4+g, rho=(c,ky)), taps j=0..2.
            // entry o = (m*64 + l)*4 + j ; co = l&15 ; rho = m*4 + (l>>4)
            for (int o = t; o < 768; o += 256) {
                int j = o & 3;
                int l = (o >> 2) & 63;
                int m = o >> 8;
                int rho = m * 4 + (l >> 4);
                int co = l & 15;
                float v = 0.f;
                if (rho < 9 && j < 3) {
                    float wv = w1[co * 27 + (rho / 3) * 9 + (rho % 3) * 3 + j];
                    v = (fabsf(wv) > delta) ? copysignf(alpha, wv) : 0.f;
                }
                tw1f[o] = (_Float16)v;
            }
            break;
        case 1:
            // conv2 B-frags for 16x16x16 f16 MFMA:
            // o = ((s*2+nt)*64 + lane)*4 + j ; ci=(lane>>4)*4+j ; co=(lane&15)+nt*16
            for (int o = t; o < 4608; o += 256) {
                int j  = o & 3;
                int ll = (o >> 2) & 63;
                int nt = (o >> 8) & 1;
                int s9 = o >> 9;
                int ci = (ll >> 4) * 4 + j;
                int co = (ll & 15) + nt * 16;
                float wv = w2[(co * 16 + ci) * 9 + s9];
                float v = (fabsf(wv) > delta) ? copysignf(alpha, wv) : 0.f;
                tw2f[o] = (_Float16)v;
            }
            break;
        default:
            for (int o = t; o < 1280; o += 256) {
                float wv = wf2[o];
                twf2[o] = (fabsf(wv) > delta) ? copysignf(alpha, wv) : 0.f;
            }
            break;
    }
}

// ---------------- stage B: delta (redundant) + masked partials -------------
__global__ void tern_stageB(const float* __restrict__ wf1,
                            const float* __restrict__ part_sum,
                            float* __restrict__ part_sa,
                            float* __restrict__ part_cnt) {
    __shared__ float red[256];
    const int t = threadIdx.x;
    const int bid = blockIdx.x;

    float v = (t < WF1_SLICES) ? part_sum[t] : 0.f;
    const float delta = 0.7f * block_reduce_256(v, red, t) / (float)WF1_N;

    const float4* src = reinterpret_cast<const float4*>(wf1 + (size_t)bid * WF1_SLICE);
    float sa = 0.f, cnt = 0.f;
#pragma unroll
    for (int j = 0; j < 4; ++j) {
        const float4 w4 = src[t + j * 256];
        float a;
        a = fabsf(w4.x); if (a > delta) { sa += a; cnt += 1.f; }
        a = fabsf(w4.y); if (a > delta) { sa += a; cnt += 1.f; }
        a = fabsf(w4.z); if (a > delta) { sa += a; cnt += 1.f; }
        a = fabsf(w4.w); if (a > delta) { sa += a; cnt += 1.f; }
    }
    const float tot_sa = block_reduce_256(sa, red, t);
    const float tot_cnt = block_reduce_256(cnt, red, t);
    if (t == 0) { part_sa[bid] = tot_sa; part_cnt[bid] = tot_cnt; }
}

// ---------------- stage C: alpha (redundant) + f16 ternary write -----------
// twf1 keeps wf1's native [n=128][k=2048] orientation (no transpose).
__global__ void tern_stageC(const float* __restrict__ wf1,
                            const float* __restrict__ part_sum,
                            const float* __restrict__ part_sa,
                            const float* __restrict__ part_cnt,
                            _Float16* __restrict__ twf1) {
    __shared__ float red[256];
    const int t = threadIdx.x;

    float v = (t < WF1_SLICES) ? part_sum[t] : 0.f;
    const float delta = 0.7f * block_reduce_256(v, red, t) / (float)WF1_N;
    v = (t < WF1_SLICES) ? part_sa[t] : 0.f;
    const float tot_sa = block_reduce_256(v, red, t);
    v = (t < WF1_SLICES) ? part_cnt[t] : 0.f;
    const float tot_cnt = block_reduce_256(v, red, t);
    const float alpha = tot_sa / fmaxf(tot_cnt, 1.0f);

    const int tid = blockIdx.x * 256 + t;  // 65536 threads x 4 elems
    const float4 w4 = reinterpret_cast<const float4*>(wf1)[tid];
    half4 hv;
    hv[0] = (_Float16)((fabsf(w4.x) > delta) ? copysignf(alpha, w4.x) : 0.f);
    hv[1] = (_Float16)((fabsf(w4.y) > delta) ? copysignf(alpha, w4.y) : 0.f);
    hv[2] = (_Float16)((fabsf(w4.z) > delta) ? copysignf(alpha, w4.z) : 0.f);
    hv[3] = (_Float16)((fabsf(w4.w) > delta) ? copysignf(alpha, w4.w) : 0.f);
    reinterpret_cast<half4*>(twf1)[tid] = hv;
}

// ---------------- fused conv1(MFMA)+pool + conv2(MFMA)+pool ----------------
// H1P=18: pixel stride 9 dwords (odd) -> conv2 A-read bank conflicts 2-way (free).
#define H1P 18
#define PSZ 3472          // 3*34*34=3468 + 4 pad f16 (6944 B, /16 ok)
#define H1SZ (18*18*H1P)  // 5832 f16 = 11664 B (/16 ok)

__global__ __launch_bounds__(256, 4)
void conv12_kernel(const float* __restrict__ x,      // [B,3,32,32]
                   const float* __restrict__ b1,     // [16]
                   const float* __restrict__ b2,     // [32]
                   const _Float16* __restrict__ tw1f,// [3][64][4] f16 B-frags
                   const _Float16* __restrict__ tw2f,// [9][2][64][4] f16 B-frags
                   _Float16* __restrict__ h2p) {     // [B,2048] f16
    __shared__ __align__(16) _Float16 PA[PSZ];          // planar f16 [3][34][34]
    __shared__ __align__(16) _Float16 PB[PSZ];          // PB[i] = PA[i+1]
    __shared__ __align__(16) _Float16 h1s[H1SZ];        // (y*18+x)*18 + ci
    __shared__ __align__(16) _Float16 h2s[2048];        // co*64 + py*8 + px
    __shared__ float b1s[16], b2s[32];

    const int t = threadIdx.x;
    const int b = blockIdx.x;
    const int wid = t >> 6, l = t & 63;

    // issue x loads FIRST so HBM latency hides under the zero phase
    float xv[12];
    {
        const float* xb = x + (size_t)b * 3072;
#pragma unroll
        for (int j = 0; j < 12; ++j) xv[j] = xb[t + j * 256];
    }
    // conv1 B-frags (L2-resident)
    half4 bfr1[3];
#pragma unroll
    for (int m = 0; m < 3; ++m)
        bfr1[m] = *reinterpret_cast<const half4*>(tw1f + (size_t)(m * 64 + l) * 4);
    if (t < 16) b1s[t] = b1[t];
    if (t < 32) b2s[t] = b2[t];

    // zero LDS via float4 (halos / garbage-tap safety)
    {
        const float4 z = {0.f, 0.f, 0.f, 0.f};
        float4* pa4 = reinterpret_cast<float4*>(PA);
        float4* pb4 = reinterpret_cast<float4*>(PB);
        float4* h14 = reinterpret_cast<float4*>(h1s);
        for (int i = t; i < PSZ * 2 / 16; i += 256) { pa4[i] = z; pb4[i] = z; }
        for (int i = t; i < H1SZ * 2 / 16; i += 256) h14[i] = z;
    }
    __syncthreads();

    // phase 1: stage x -> planar f16 (PA) + shifted copy (PB)
    {
#pragma unroll
        for (int j = 0; j < 12; ++j) {
            const int i = t + j * 256;
            const int c = i >> 10, rem = i & 1023;
            const int iy = rem >> 5, ix = rem & 31;
            const _Float16 h = (_Float16)xv[j];
            const int idx = (c * 34 + iy + 1) * 34 + ix + 1;
            PA[idx] = h;
            PB[idx - 1] = h;
        }
    }
    __syncthreads();

    // phase 2: conv1 via 3x chained 16x16x16 MFMA (K-rows (c,ky) x 4 taps)
    {
        const int r15 = l & 15, g = l >> 4;
        const int p = r15 & 1;
        int laneIdx[3];
#pragma unroll
        for (int m = 0; m < 3; ++m) {
            int rho = m * 4 + g;
            if (rho > 8) rho = 0;  // dead rows: B is zero there, any finite read ok
            const int c = rho / 3, ky = rho % 3;
            laneIdx[m] = ((c * 34 + ky) * 34 + r15 - p) >> 1;
        }
        const unsigned* basep = p ? reinterpret_cast<const unsigned*>(PB)
                                  : reinterpret_cast<const unsigned*>(PA);
        const float bia = b1s[r15];

#pragma unroll 1
        for (int i = 0; i < 8; ++i) {
            const int P = wid * 8 + i;
            const int py = P >> 1, xh = P & 1;
            const int x0 = xh * 16;
            f32x4 accA = {0.f, 0.f, 0.f, 0.f};
            f32x4 accB = {0.f, 0.f, 0.f, 0.f};
#pragma unroll
            for (int h2 = 0; h2 < 2; ++h2) {
                const int y = 2 * py + h2;
                const int uoff = (y * 34 + x0) >> 1;
                f32x4 acc = {0.f, 0.f, 0.f, 0.f};
#pragma unroll
                for (int m = 0; m < 3; ++m) {
                    const unsigned* q = basep + laneIdx[m] + uoff;
                    u32x2 d;
                    d.x = q[0];
                    d.y = q[1];
                    const half4 a = __builtin_bit_cast(half4, d);
                    acc = __builtin_amdgcn_mfma_f32_16x16x16f16(a, bfr1[m], acc, 0, 0, 0);
                }
                if (h2 == 0) accA = acc; else accB = acc;
            }
            // 2x2 maxpool on regs (x = g*4 + reg), then bias+relu
            float e0 = fmaxf(fmaxf(accA[0], accA[1]), fmaxf(accB[0], accB[1]));
            float e1 = fmaxf(fmaxf(accA[2], accA[3]), fmaxf(accB[2], accB[3]));
            e0 = fmaxf(e0 + bia, 0.f);
            e1 = fmaxf(e1 + bia, 0.f);
            const int px0 = xh * 8 + g * 2;
            const int pix = (py + 1) * 18 + (px0 + 1);
            h1s[pix * H1P + r15]       = (_Float16)e0;
            h1s[(pix + 1) * H1P + r15] = (_Float16)e1;
        }
    }

    // conv2 B-frags (global, per-lane 8B, coalesced, L2-resident)
    half4 bfr[9][2];
#pragma unroll
    for (int s = 0; s < 9; ++s)
#pragma unroll
        for (int nt = 0; nt < 2; ++nt)
            bfr[s][nt] = *reinterpret_cast<const half4*>(
                tw2f + (size_t)((s * 2 + nt) * 64 + l) * 4);
    __syncthreads();

    // phase 3: conv2 (9-shift MFMA) + bias + relu + pool.
    // Register-blocked: preload the lane's 6 rows x 3 cols of h1 fragments
    // ONCE (18 DS ops instead of 36), then run all 72 MFMAs from registers.
    {
        const int xq = l & 15, g = l >> 4;
        const unsigned* h1u = reinterpret_cast<const unsigned*>(h1s);
        u32x2 pre[6][3];
#pragma unroll
        for (int r = 0; r < 6; ++r)
#pragma unroll
            for (int cc = 0; cc < 3; ++cc) {
                const unsigned* q = h1u + ((wid * 4 + r) * 18 + xq + cc) * 9 + g * 2;
                pre[r][cc].x = q[0];
                pre[r][cc].y = q[1];
            }
        float sav[2][2];
#pragma unroll
        for (int yy = 0; yy < 4; ++yy) {
            f32x4 acc0 = {0.f, 0.f, 0.f, 0.f};
            f32x4 acc1 = {0.f, 0.f, 0.f, 0.f};
#pragma unroll
            for (int dy = 0; dy < 3; ++dy)
#pragma unroll
                for (int dx = 0; dx < 3; ++dx) {
                    const int s = dy * 3 + dx;
                    const half4 a = __builtin_bit_cast(half4, pre[yy + dy][dx]);
                    acc0 = __builtin_amdgcn_mfma_f32_16x16x16f16(a, bfr[s][0], acc0, 0, 0, 0);
                    acc1 = __builtin_amdgcn_mfma_f32_16x16x16f16(a, bfr[s][1], acc1, 0, 0, 0);
                }
            // x-pool: lane regs are pixels x = g*4 + r
            const float p00 = fmaxf(acc0[0], acc0[1]);
            const float p01 = fmaxf(acc0[2], acc0[3]);
            const float p10 = fmaxf(acc1[0], acc1[1]);
            const float p11 = fmaxf(acc1[2], acc1[3]);
            if ((yy & 1) == 0) {
                sav[0][0] = p00; sav[0][1] = p01;
                sav[1][0] = p10; sav[1][1] = p11;
            } else {
                const int py = (wid * 4 + yy) >> 1;
                const float v00 = fmaxf(fmaxf(sav[0][0], p00) + b2s[xq], 0.f);
                const float v01 = fmaxf(fmaxf(sav[0][1], p01) + b2s[xq], 0.f);
                const float v10 = fmaxf(fmaxf(sav[1][0], p10) + b2s[xq + 16], 0.f);
                const float v11 = fmaxf(fmaxf(sav[1][1], p11) + b2s[xq + 16], 0.f);
                unsigned* h2u = reinterpret_cast<unsigned*>(h2s);
                h2u[xq * 32 + py * 4 + g]        = pk16(v00, v01);
                h2u[(xq + 16) * 32 + py * 4 + g] = pk16(v10, v11);
            }
        }
    }
    __syncthreads();

    // phase 4: h2s -> global (coalesced 16B/thread)
    {
        const float4 v = reinterpret_cast<const float4*>(h2s)[t];
        reinterpret_cast<float4*>(h2p + (size_t)b * 2048)[t] = v;
    }
}

// ---------------- fc1 (MFMA f16, K-split over 16 waves) + fc2 fused --------
// grid = B/16 blocks x 1024 threads. Wave w owns K-chunk [w*128,(w+1)*128).
// No LDS staging in K-loop; fragments loaded straight from global.
__global__ __launch_bounds__(1024, 4)
void fc_kernel(const _Float16* __restrict__ h2p,   // [B,2048]
               const _Float16* __restrict__ twf1,  // [128 n][2048 k]
               const float* __restrict__ bf1,      // [128]
               const float* __restrict__ twf2,     // [10][128]
               const float* __restrict__ bf2,      // [10]
               float* __restrict__ out) {          // [B,10]
    __shared__ float red[8][2048];                 // 64 KB reduction buffer

    const int t = threadIdx.x;
    const int wid = t >> 6, l = t & 63;
    const int lx = l & 15, g = l >> 4;
    const int m0 = blockIdx.x * 16;

    f32x4 acc[8];
#pragma unroll
    for (int nt = 0; nt < 8; ++nt) acc[nt] = (f32x4){0.f, 0.f, 0.f, 0.f};

    const int kb = wid * 128;
#pragma unroll
    for (int it = 0; it < 4; ++it) {
        const int k0 = kb + it * 32;
        const half8 a = *reinterpret_cast<const half8*>(
            h2p + (size_t)(m0 + lx) * 2048 + k0 + g * 8);
#pragma unroll
        for (int nt = 0; nt < 8; ++nt) {
            const half8 bb = *reinterpret_cast<const half8*>(
                twf1 + (size_t)(nt * 16 + lx) * 2048 + k0 + g * 8);
            acc[nt] = __builtin_amdgcn_mfma_f32_16x16x32_f16(a, bb, acc[nt], 0, 0, 0);
        }
    }

    // tree-reduce 16 wave partials -> wave 0
    for (int h = 8; h >= 1; h >>= 1) {
        if (wid >= h && wid < 2 * h) {
            float* dst = &red[wid - h][0];
#pragma unroll
            for (int nt = 0; nt < 8; ++nt)
                *reinterpret_cast<f32x4*>(dst + nt * 256 + l * 4) = acc[nt];
        }
        __syncthreads();
        if (wid < h) {
            const float* srcp = &red[wid][0];
#pragma unroll
            for (int nt = 0; nt < 8; ++nt) {
                const f32x4 v = *reinterpret_cast<const f32x4*>(srcp + nt * 256 + l * 4);
                acc[nt] += v;
            }
        }
        __syncthreads();
    }

    // wave 0: bias + relu -> Hs (stored in red[0])
    if (wid == 0) {
#pragma unroll
        for (int nt = 0; nt < 8; ++nt) {
            const int col = nt * 16 + lx;
            const float bias = bf1[col];
#pragma unroll
            for (int r = 0; r < 4; ++r)
                red[0][(g * 4 + r) * 128 + col] = fmaxf(acc[nt][r] + bias, 0.f);
        }
    }
    __syncthreads();

    // fc2: 160 outputs (16 rows x 10)
    if (t < 160) {
        const int m = t / 10, n = t % 10;
        float a = bf2[n];
#pragma unroll 8
        for (int k = 0; k < 128; ++k) a += red[0][m * 128 + k] * twf2[n * 128 + k];
        out[(size_t)(m0 + m) * 10 + n] = a;
    }
}

// ---------------------------------------------------------------------------
extern "C" void kernel_launch(void* const* d_in, const int* in_sizes, int n_in,
                              void* d_out, int out_size, void* d_ws, size_t ws_size,
                              hipStream_t stream) {
    const float* x   = (const float*)d_in[0];
    const float* w1  = (const float*)d_in[1];
    const float* b1  = (const float*)d_in[2];
    const float* w2  = (const float*)d_in[3];
    const float* b2  = (const float*)d_in[4];
    const float* wf1 = (const float*)d_in[5];
    const float* bf1 = (const float*)d_in[6];
    const float* wf2 = (const float*)d_in[7];
    const float* bf2 = (const float*)d_in[8];
    float* out = (float*)d_out;
    const int B = in_sizes[0] / (3 * 32 * 32);  // 4096

    char* ws = (char*)d_ws;
    _Float16*  tw1f  = (_Float16*)(ws + 0);
    _Float16*  tw2f  = (_Float16*)(ws + 1536);
    _Float16*  twf1  = (_Float16*)(ws + 10752);
    float*     twf2  = (float*)(ws + 535040);
    _Float16*  h2p   = (_Float16*)(ws + 540160);
    float*     part_sum = (float*)(ws + 17317376);
    float*     part_sa  = part_sum + 64;
    float*     part_cnt = part_sa + 64;

    tern_stageA<<<WF1_SLICES + 3, 256, 0, stream>>>(w1, w2, wf1, wf2,
                                                    tw1f, tw2f, twf2, part_sum);
    tern_stageB<<<WF1_SLICES, 256, 0, stream>>>(wf1, part_sum, part_sa, part_cnt);
    tern_stageC<<<256, 256, 0, stream>>>(wf1, part_sum, part_sa, part_cnt, twf1);
    conv12_kernel<<<B, 256, 0, stream>>>(x, b1, b2, tw1f, tw2f, h2p);
    fc_kernel<<<B / 16, 1024, 0, stream>>>(h2p, twf1, bf1, twf2, bf2, out);
}

// Round 10
// 74.843 us; speedup vs baseline: 9.8159x; 1.0145x over previous
//
#include <hip/hip_runtime.h>
#include <math.h>

// ---------------------------------------------------------------------------
// SimpleTernaryNet forward, MFMA-f16 for conv1 + conv2 + fc1.
//   tern(w) -> conv3x3(3->16)+b+relu -> maxpool2      (f16 MFMA, 9-row K=27)
//           -> conv3x3(16->32)+b+relu -> maxpool2     (f16 MFMA, 9-shift)
//           -> fc(2048->128)+b+relu                   (f16 MFMA, K-split 16 waves)
//           -> fc(128->10)+b                          (fp32 VALU)
//
// Round-9b: fix cvt_pkrtz return-type mismatch (bit_cast to unsigned).
// conv12 staging vectorized (float4 loads + cvt_pkrtz + parity-aware u32 LDS
// stores); conv2 in the verified round-6 pointer form; launch_bounds(256,5).
//
// ws layout (bytes):
//   [0)         tw1f   f16 [3][64][4] conv1 B-frags   1536 B
//   [1536)      tw2f   f16 [9][2][64][4] conv2 B-frags 9216 B
//   [10752)     twf1   f16 [128 n][2048 k]            524288 B
//   [535040)    twf2   f32 [10][128]                  5120 B
//   [540160)    h2p    f16 [4096][2048]               16777216 B
//   [17317376)  partials f32 sum[64], sa[64], cnt[64]
// ---------------------------------------------------------------------------

typedef _Float16 half2v __attribute__((ext_vector_type(2)));
typedef _Float16 half4  __attribute__((ext_vector_type(4)));
typedef _Float16 half8  __attribute__((ext_vector_type(8)));
typedef float    f32x4  __attribute__((ext_vector_type(4)));
typedef unsigned u32x2  __attribute__((ext_vector_type(2)));

#define WF1_N 262144
#define WF1_SLICES 64
#define WF1_SLICE 4096

__device__ __forceinline__ float block_reduce_256(float v, float* red, int t) {
    red[t] = v; __syncthreads();
    for (int o = 128; o > 0; o >>= 1) {
        if (t < o) red[t] += red[t + o];
        __syncthreads();
    }
    float r = red[0]; __syncthreads();
    return r;
}

__device__ __forceinline__ unsigned pk16(float a, float b) {
    half2v h;
    h[0] = (_Float16)a;
    h[1] = (_Float16)b;
    return __builtin_bit_cast(unsigned, h);
}

// ---------------- stage A: wf1 partial |sum| + small tensors complete ------
__global__ void tern_stageA(const float* __restrict__ w1,
                            const float* __restrict__ w2,
                            const float* __restrict__ wf1,
                            const float* __restrict__ wf2,
                            _Float16* __restrict__ tw1f,
                            _Float16* __restrict__ tw2f,
                            float* __restrict__ twf2,
                            float* __restrict__ part_sum) {
    __shared__ float red[256];
    const int t = threadIdx.x;
    const int bid = blockIdx.x;

    if (bid < WF1_SLICES) {
        const float4* src = reinterpret_cast<const float4*>(wf1 + (size_t)bid * WF1_SLICE);
        float s = 0.f;
#pragma unroll
        for (int j = 0; j < 4; ++j) {
            const float4 v = src[t + j * 256];
            s += fabsf(v.x) + fabsf(v.y) + fabsf(v.z) + fabsf(v.w);
        }
        const float tot = block_reduce_256(s, red, t);
        if (t == 0) part_sum[bid] = tot;
        return;
    }

    const float* w;
    int n;
    const int which = bid - WF1_SLICES;  // 0:w1 1:w2 2:wf2
    switch (which) {
        case 0: w = w1;  n = 432;  break;
        case 1: w = w2;  n = 4608; break;
        default: w = wf2; n = 1280; break;
    }
    float s = 0.f;
    for (int i = t; i < n; i += 256) s += fabsf(w[i]);
    const float delta = 0.7f * block_reduce_256(s, red, t) / (float)n;
    float sa = 0.f, cnt = 0.f;
    for (int i = t; i < n; i += 256) {
        float a = fabsf(w[i]);
        if (a > delta) { sa += a; cnt += 1.f; }
    }
    const float tot_sa = block_reduce_256(sa, red, t);
    const float tot_cnt = block_reduce_256(cnt, red, t);
    const float alpha = tot_sa / fmaxf(tot_cnt, 1.0f);

    switch (which) {
        case 0:
            // conv1 B-frags: 3 MFMAs (K-rows rho=m*4+g, rho=(c,ky)), taps j=0..2.
            // entry o = (m*64 + l)*4 + j ; co = l&15 ; rho = m*4 + (l>>4)
            for (int o = t; o < 768; o += 256) {
                int j = o & 3;
                int l = (o >> 2) & 63;
                int m = o >> 8;
                int rho = m * 4 + (l >> 4);
                int co = l & 15;
                float v = 0.f;
                if (rho < 9 && j < 3) {
                    float wv = w1[co * 27 + (rho / 3) * 9 + (rho % 3) * 3 + j];
                    v = (fabsf(wv) > delta) ? copysignf(alpha, wv) : 0.f;
                }
                tw1f[o] = (_Float16)v;
            }
            break;
        case 1:
            // conv2 B-frags for 16x16x16 f16 MFMA:
            // o = ((s*2+nt)*64 + lane)*4 + j ; ci=(lane>>4)*4+j ; co=(lane&15)+nt*16
            for (int o = t; o < 4608; o += 256) {
                int j  = o & 3;
                int ll = (o >> 2) & 63;
                int nt = (o >> 8) & 1;
                int s9 = o >> 9;
                int ci = (ll >> 4) * 4 + j;
                int co = (ll & 15) + nt * 16;
                float wv = w2[(co * 16 + ci) * 9 + s9];
                float v = (fabsf(wv) > delta) ? copysignf(alpha, wv) : 0.f;
                tw2f[o] = (_Float16)v;
            }
            break;
        default:
            for (int o = t; o < 1280; o += 256) {
                float wv = wf2[o];
                twf2[o] = (fabsf(wv) > delta) ? copysignf(alpha, wv) : 0.f;
            }
            break;
    }
}

// ---------------- stage B: delta (redundant) + masked partials -------------
__global__ void tern_stageB(const float* __restrict__ wf1,
                            const float* __restrict__ part_sum,
                            float* __restrict__ part_sa,
                            float* __restrict__ part_cnt) {
    __shared__ float red[256];
    const int t = threadIdx.x;
    const int bid = blockIdx.x;

    float v = (t < WF1_SLICES) ? part_sum[t] : 0.f;
    const float delta = 0.7f * block_reduce_256(v, red, t) / (float)WF1_N;

    const float4* src = reinterpret_cast<const float4*>(wf1 + (size_t)bid * WF1_SLICE);
    float sa = 0.f, cnt = 0.f;
#pragma unroll
    for (int j = 0; j < 4; ++j) {
        const float4 w4 = src[t + j * 256];
        float a;
        a = fabsf(w4.x); if (a > delta) { sa += a; cnt += 1.f; }
        a = fabsf(w4.y); if (a > delta) { sa += a; cnt += 1.f; }
        a = fabsf(w4.z); if (a > delta) { sa += a; cnt += 1.f; }
        a = fabsf(w4.w); if (a > delta) { sa += a; cnt += 1.f; }
    }
    const float tot_sa = block_reduce_256(sa, red, t);
    const float tot_cnt = block_reduce_256(cnt, red, t);
    if (t == 0) { part_sa[bid] = tot_sa; part_cnt[bid] = tot_cnt; }
}

// ---------------- stage C: alpha (redundant) + f16 ternary write -----------
// twf1 keeps wf1's native [n=128][k=2048] orientation (no transpose).
__global__ void tern_stageC(const float* __restrict__ wf1,
                            const float* __restrict__ part_sum,
                            const float* __restrict__ part_sa,
                            const float* __restrict__ part_cnt,
                            _Float16* __restrict__ twf1) {
    __shared__ float red[256];
    const int t = threadIdx.x;

    float v = (t < WF1_SLICES) ? part_sum[t] : 0.f;
    const float delta = 0.7f * block_reduce_256(v, red, t) / (float)WF1_N;
    v = (t < WF1_SLICES) ? part_sa[t] : 0.f;
    const float tot_sa = block_reduce_256(v, red, t);
    v = (t < WF1_SLICES) ? part_cnt[t] : 0.f;
    const float tot_cnt = block_reduce_256(v, red, t);
    const float alpha = tot_sa / fmaxf(tot_cnt, 1.0f);

    const int tid = blockIdx.x * 256 + t;  // 65536 threads x 4 elems
    const float4 w4 = reinterpret_cast<const float4*>(wf1)[tid];
    half4 hv;
    hv[0] = (_Float16)((fabsf(w4.x) > delta) ? copysignf(alpha, w4.x) : 0.f);
    hv[1] = (_Float16)((fabsf(w4.y) > delta) ? copysignf(alpha, w4.y) : 0.f);
    hv[2] = (_Float16)((fabsf(w4.z) > delta) ? copysignf(alpha, w4.z) : 0.f);
    hv[3] = (_Float16)((fabsf(w4.w) > delta) ? copysignf(alpha, w4.w) : 0.f);
    reinterpret_cast<half4*>(twf1)[tid] = hv;
}

// ---------------- fused conv1(MFMA)+pool + conv2(MFMA)+pool ----------------
// H1P=18: pixel stride 9 dwords (odd) -> conv2 A-read bank conflicts 2-way (free).
#define H1P 18
#define PSZ 3472          // 3*34*34=3468 + 4 pad f16 (6944 B, /16 ok)
#define H1SZ (18*18*H1P)  // 5832 f16 = 11664 B (/16 ok)

__global__ __launch_bounds__(256, 5)
void conv12_kernel(const float* __restrict__ x,      // [B,3,32,32]
                   const float* __restrict__ b1,     // [16]
                   const float* __restrict__ b2,     // [32]
                   const _Float16* __restrict__ tw1f,// [3][64][4] f16 B-frags
                   const _Float16* __restrict__ tw2f,// [9][2][64][4] f16 B-frags
                   _Float16* __restrict__ h2p) {     // [B,2048] f16
    __shared__ __align__(16) _Float16 PA[PSZ];          // planar f16 [3][34][34]
    __shared__ __align__(16) _Float16 PB[PSZ];          // PB[i] = PA[i+1]
    __shared__ __align__(16) _Float16 h1s[H1SZ];        // (y*18+x)*18 + ci
    __shared__ __align__(16) _Float16 h2s[2048];        // co*64 + py*8 + px
    __shared__ float b1s[16], b2s[32];

    const int t = threadIdx.x;
    const int b = blockIdx.x;
    const int wid = t >> 6, l = t & 63;

    // issue x loads FIRST (3x float4, coalesced) so HBM latency hides
    // under the zero phase
    float4 xv4[3];
    {
        const float4* xb4 = reinterpret_cast<const float4*>(x + (size_t)b * 3072);
#pragma unroll
        for (int j = 0; j < 3; ++j) xv4[j] = xb4[t + j * 256];
    }
    // conv1 B-frags (L2-resident)
    half4 bfr1[3];
#pragma unroll
    for (int m = 0; m < 3; ++m)
        bfr1[m] = *reinterpret_cast<const half4*>(tw1f + (size_t)(m * 64 + l) * 4);
    if (t < 16) b1s[t] = b1[t];
    if (t < 32) b2s[t] = b2[t];

    // zero LDS via float4 (halos / garbage-tap safety)
    {
        const float4 z = {0.f, 0.f, 0.f, 0.f};
        float4* pa4 = reinterpret_cast<float4*>(PA);
        float4* pb4 = reinterpret_cast<float4*>(PB);
        float4* h14 = reinterpret_cast<float4*>(h1s);
        for (int i = t; i < PSZ * 2 / 16; i += 256) { pa4[i] = z; pb4[i] = z; }
        for (int i = t; i < H1SZ * 2 / 16; i += 256) h14[i] = z;
    }
    __syncthreads();

    // phase 1: stage x -> planar f16 PA + shifted copy PB.
    // Each thread handles 3 groups of 4 consecutive x-pixels.
    // idx = rowbase(even) + 1 + ix (ix%4==0) is ALWAYS ODD ->
    //   PB[idx-1..idx+2]: two aligned u32 stores (w0, w1)
    //   PA[idx..idx+3]:   b16(x0), u32(x1|x2), b16(x3)
    {
#pragma unroll
        for (int j = 0; j < 3; ++j) {
            const int f = t + j * 256;           // float4 group id, 768 total
            const int c = f >> 8, rem = f & 255;
            const int iy = rem >> 3, ix = (rem & 7) << 2;
            const int idx = ((c * 34) + iy + 1) * 34 + 1 + ix;
            const float4 v = xv4[j];
            const unsigned w0 = __builtin_bit_cast(unsigned, __builtin_amdgcn_cvt_pkrtz(v.x, v.y));
            const unsigned w1 = __builtin_bit_cast(unsigned, __builtin_amdgcn_cvt_pkrtz(v.z, v.w));
            const half2v h0 = __builtin_bit_cast(half2v, w0);
            const half2v h1 = __builtin_bit_cast(half2v, w1);
            *reinterpret_cast<unsigned*>(&PB[idx - 1]) = w0;
            *reinterpret_cast<unsigned*>(&PB[idx + 1]) = w1;
            PA[idx] = h0[0];
            *reinterpret_cast<unsigned*>(&PA[idx + 1]) = (w0 >> 16) | (w1 << 16);
            PA[idx + 3] = h1[1];
        }
    }
    __syncthreads();

    // phase 2: conv1 via 3x chained 16x16x16 MFMA (K-rows (c,ky) x 4 taps)
    {
        const int r15 = l & 15, g = l >> 4;
        const int p = r15 & 1;
        int laneIdx[3];
#pragma unroll
        for (int m = 0; m < 3; ++m) {
            int rho = m * 4 + g;
            if (rho > 8) rho = 0;  // dead rows: B is zero there, any finite read ok
            const int c = rho / 3, ky = rho % 3;
            laneIdx[m] = ((c * 34 + ky) * 34 + r15 - p) >> 1;
        }
        const unsigned* basep = p ? reinterpret_cast<const unsigned*>(PB)
                                  : reinterpret_cast<const unsigned*>(PA);
        const float bia = b1s[r15];

#pragma unroll 1
        for (int i = 0; i < 8; ++i) {
            const int P = wid * 8 + i;
            const int py = P >> 1, xh = P & 1;
            const int x0 = xh * 16;
            f32x4 accA = {0.f, 0.f, 0.f, 0.f};
            f32x4 accB = {0.f, 0.f, 0.f, 0.f};
#pragma unroll
            for (int h2 = 0; h2 < 2; ++h2) {
                const int y = 2 * py + h2;
                const int uoff = (y * 34 + x0) >> 1;
                f32x4 acc = {0.f, 0.f, 0.f, 0.f};
#pragma unroll
                for (int m = 0; m < 3; ++m) {
                    const unsigned* q = basep + laneIdx[m] + uoff;
                    u32x2 d;
                    d.x = q[0];
                    d.y = q[1];
                    const half4 a = __builtin_bit_cast(half4, d);
                    acc = __builtin_amdgcn_mfma_f32_16x16x16f16(a, bfr1[m], acc, 0, 0, 0);
                }
                if (h2 == 0) accA = acc; else accB = acc;
            }
            // 2x2 maxpool on regs (x = g*4 + reg), then bias+relu
            float e0 = fmaxf(fmaxf(accA[0], accA[1]), fmaxf(accB[0], accB[1]));
            float e1 = fmaxf(fmaxf(accA[2], accA[3]), fmaxf(accB[2], accB[3]));
            e0 = fmaxf(e0 + bia, 0.f);
            e1 = fmaxf(e1 + bia, 0.f);
            const int px0 = xh * 8 + g * 2;
            const int pix = (py + 1) * 18 + (px0 + 1);
            h1s[pix * H1P + r15]       = (_Float16)e0;
            h1s[(pix + 1) * H1P + r15] = (_Float16)e1;
        }
    }

    // conv2 B-frags (global, per-lane 8B, coalesced, L2-resident)
    half4 bfr[9][2];
#pragma unroll
    for (int s = 0; s < 9; ++s)
#pragma unroll
        for (int nt = 0; nt < 2; ++nt)
            bfr[s][nt] = *reinterpret_cast<const half4*>(
                tw2f + (size_t)((s * 2 + nt) * 64 + l) * 4);
    __syncthreads();

    // phase 3: conv2 (9-shift MFMA) + bias + relu + pool
    {
        const int xq = l & 15, g = l >> 4;
        const unsigned* h1u = reinterpret_cast<const unsigned*>(h1s);
        float sav[2][2];
#pragma unroll
        for (int yy = 0; yy < 4; ++yy) {
            const int y = wid * 4 + yy;
            // per-lane base; all 9 taps are constant dword offsets from here
            const unsigned* qb = h1u + (y * 18 + xq) * 9 + g * 2;
            f32x4 acc0 = {0.f, 0.f, 0.f, 0.f};
            f32x4 acc1 = {0.f, 0.f, 0.f, 0.f};
#pragma unroll
            for (int s = 0; s < 9; ++s) {
                const int dy = s / 3, dx = s % 3;
                const int off = (dy * 18 + dx) * 9;
                u32x2 d;
                d.x = qb[off];
                d.y = qb[off + 1];
                const half4 a = __builtin_bit_cast(half4, d);
                acc0 = __builtin_amdgcn_mfma_f32_16x16x16f16(a, bfr[s][0], acc0, 0, 0, 0);
                acc1 = __builtin_amdgcn_mfma_f32_16x16x16f16(a, bfr[s][1], acc1, 0, 0, 0);
            }
            // x-pool: lane regs are pixels x = g*4 + r
            const float p00 = fmaxf(acc0[0], acc0[1]);
            const float p01 = fmaxf(acc0[2], acc0[3]);
            const float p10 = fmaxf(acc1[0], acc1[1]);
            const float p11 = fmaxf(acc1[2], acc1[3]);
            if ((yy & 1) == 0) {
                sav[0][0] = p00; sav[0][1] = p01;
                sav[1][0] = p10; sav[1][1] = p11;
            } else {
                const int py = (wid * 4 + yy) >> 1;
                const float v00 = fmaxf(fmaxf(sav[0][0], p00) + b2s[xq], 0.f);
                const float v01 = fmaxf(fmaxf(sav[0][1], p01) + b2s[xq], 0.f);
                const float v10 = fmaxf(fmaxf(sav[1][0], p10) + b2s[xq + 16], 0.f);
                const float v11 = fmaxf(fmaxf(sav[1][1], p11) + b2s[xq + 16], 0.f);
                unsigned* h2u = reinterpret_cast<unsigned*>(h2s);
                h2u[xq * 32 + py * 4 + g]        = pk16(v00, v01);
                h2u[(xq + 16) * 32 + py * 4 + g] = pk16(v10, v11);
            }
        }
    }
    __syncthreads();

    // phase 4: h2s -> global (coalesced 16B/thread)
    {
        const float4 v = reinterpret_cast<const float4*>(h2s)[t];
        reinterpret_cast<float4*>(h2p + (size_t)b * 2048)[t] = v;
    }
}

// ---------------- fc1 (MFMA f16, K-split over 16 waves) + fc2 fused --------
// grid = B/16 blocks x 1024 threads. Wave w owns K-chunk [w*128,(w+1)*128).
// No LDS staging in K-loop; fragments loaded straight from global.
__global__ __launch_bounds__(1024, 4)
void fc_kernel(const _Float16* __restrict__ h2p,   // [B,2048]
               const _Float16* __restrict__ twf1,  // [128 n][2048 k]
               const float* __restrict__ bf1,      // [128]
               const float* __restrict__ twf2,     // [10][128]
               const float* __restrict__ bf2,      // [10]
               float* __restrict__ out) {          // [B,10]
    __shared__ float red[8][2048];                 // 64 KB reduction buffer

    const int t = threadIdx.x;
    const int wid = t >> 6, l = t & 63;
    const int lx = l & 15, g = l >> 4;
    const int m0 = blockIdx.x * 16;

    f32x4 acc[8];
#pragma unroll
    for (int nt = 0; nt < 8; ++nt) acc[nt] = (f32x4){0.f, 0.f, 0.f, 0.f};

    const int kb = wid * 128;
#pragma unroll
    for (int it = 0; it < 4; ++it) {
        const int k0 = kb + it * 32;
        const half8 a = *reinterpret_cast<const half8*>(
            h2p + (size_t)(m0 + lx) * 2048 + k0 + g * 8);
#pragma unroll
        for (int nt = 0; nt < 8; ++nt) {
            const half8 bb = *reinterpret_cast<const half8*>(
                twf1 + (size_t)(nt * 16 + lx) * 2048 + k0 + g * 8);
            acc[nt] = __builtin_amdgcn_mfma_f32_16x16x32_f16(a, bb, acc[nt], 0, 0, 0);
        }
    }

    // tree-reduce 16 wave partials -> wave 0
    for (int h = 8; h >= 1; h >>= 1) {
        if (wid >= h && wid < 2 * h) {
            float* dst = &red[wid - h][0];
#pragma unroll
            for (int nt = 0; nt < 8; ++nt)
                *reinterpret_cast<f32x4*>(dst + nt * 256 + l * 4) = acc[nt];
        }
        __syncthreads();
        if (wid < h) {
            const float* srcp = &red[wid][0];
#pragma unroll
            for (int nt = 0; nt < 8; ++nt) {
                const f32x4 v = *reinterpret_cast<const f32x4*>(srcp + nt * 256 + l * 4);
                acc[nt] += v;
            }
        }
        __syncthreads();
    }

    // wave 0: bias + relu -> Hs (stored in red[0])
    if (wid == 0) {
#pragma unroll
        for (int nt = 0; nt < 8; ++nt) {
            const int col = nt * 16 + lx;
            const float bias = bf1[col];
#pragma unroll
            for (int r = 0; r < 4; ++r)
                red[0][(g * 4 + r) * 128 + col] = fmaxf(acc[nt][r] + bias, 0.f);
        }
    }
    __syncthreads();

    // fc2: 160 outputs (16 rows x 10)
    if (t < 160) {
        const int m = t / 10, n = t % 10;
        float a = bf2[n];
#pragma unroll 8
        for (int k = 0; k < 128; ++k) a += red[0][m * 128 + k] * twf2[n * 128 + k];
        out[(size_t)(m0 + m) * 10 + n] = a;
    }
}

// ---------------------------------------------------------------------------
extern "C" void kernel_launch(void* const* d_in, const int* in_sizes, int n_in,
                              void* d_out, int out_size, void* d_ws, size_t ws_size,
                              hipStream_t stream) {
    const float* x   = (const float*)d_in[0];
    const float* w1  = (const float*)d_in[1];
    const float* b1  = (const float*)d_in[2];
    const float* w2  = (const float*)d_in[3];
    const float* b2  = (const float*)d_in[4];
    const float* wf1 = (const float*)d_in[5];
    const float* bf1 = (const float*)d_in[6];
    const float* wf2 = (const float*)d_in[7];
    const float* bf2 = (const float*)d_in[8];
    float* out = (float*)d_out;
    const int B = in_sizes[0] / (3 * 32 * 32);  // 4096

    char* ws = (char*)d_ws;
    _Float16*  tw1f  = (_Float16*)(ws + 0);
    _Float16*  tw2f  = (_Float16*)(ws + 1536);
    _Float16*  twf1  = (_Float16*)(ws + 10752);
    float*     twf2  = (float*)(ws + 535040);
    _Float16*  h2p   = (_Float16*)(ws + 540160);
    float*     part_sum = (float*)(ws + 17317376);
    float*     part_sa  = part_sum + 64;
    float*     part_cnt = part_sa + 64;

    tern_stageA<<<WF1_SLICES + 3, 256, 0, stream>>>(w1, w2, wf1, wf2,
                                                    tw1f, tw2f, twf2, part_sum);
    tern_stageB<<<WF1_SLICES, 256, 0, stream>>>(wf1, part_sum, part_sa, part_cnt);
    tern_stageC<<<256, 256, 0, stream>>>(wf1, part_sum, part_sa, part_cnt, twf1);
    conv12_kernel<<<B, 256, 0, stream>>>(x, b1, b2, tw1f, tw2f, h2p);
    fc_kernel<<<B / 16, 1024, 0, stream>>>(h2p, twf1, bf1, twf2, bf2, out);
}